// Round 5
// baseline (333.154 us; speedup 1.0000x reference)
//
#include <hip/hip_runtime.h>

#define NB 4
#define NT 40000
#define NS0 30000
#define ND0 15000
#define NE0 360000
#define ND1 7500
#define NE1 180000
#define NEG 0.2f

__device__ __forceinline__ unsigned short f2bf(float f) {
    unsigned u = __float_as_uint(f);
    u += 0x7FFF + ((u >> 16) & 1);          // round-to-nearest-even
    return (unsigned short)(u >> 16);
}
__device__ __forceinline__ float bf2f(unsigned short s) {
    return __uint_as_float((unsigned)s << 16);
}

// ---------------- zero degree histograms -----------------------------------
__global__ void kz_zero(int* __restrict__ deg0, int* __restrict__ deg1) {
    int t = blockIdx.x * blockDim.x + threadIdx.x;
    if (t < ND0) deg0[t] = 0;
    if (t < ND1) deg1[t] = 0;
}

// ---------------- histogram of edge destinations ---------------------------
__global__ void kh_hist(const int* __restrict__ edst0, const int* __restrict__ edst1,
                        int* __restrict__ deg0, int* __restrict__ deg1) {
    int t = blockIdx.x * blockDim.x + threadIdx.x;
    if (t < NE0) atomicAdd(&deg0[edst0[t]], 1);
    else if (t < NE0 + NE1) atomicAdd(&deg1[edst1[t - NE0]], 1);
}

// ---------------- exclusive scan (one block per layer) ---------------------
__device__ void scan_block(const int* __restrict__ deg, int* __restrict__ off,
                           int* __restrict__ cur, int n) {
    __shared__ int s[1024];
    int t = threadIdx.x;
    int chunk = (n + 1023) / 1024;
    int base = t * chunk;
    int mysum = 0;
    for (int i = 0; i < chunk; ++i) {
        int idx = base + i;
        if (idx < n) mysum += deg[idx];
    }
    s[t] = mysum;
    __syncthreads();
    for (int o = 1; o < 1024; o <<= 1) {
        int v = (t >= o) ? s[t - o] : 0;
        __syncthreads();
        s[t] += v;
        __syncthreads();
    }
    int run = s[t] - mysum;   // exclusive prefix of my chunk
    for (int i = 0; i < chunk; ++i) {
        int idx = base + i;
        if (idx < n) {
            off[idx] = run;
            cur[idx] = run;
            run += deg[idx];
        }
    }
}

__global__ void ks_scan(const int* __restrict__ deg0, int* __restrict__ off0, int* __restrict__ cur0,
                        const int* __restrict__ deg1, int* __restrict__ off1, int* __restrict__ cur1) {
    if (blockIdx.x == 0) scan_block(deg0, off0, cur0, ND0);
    else                 scan_block(deg1, off1, cur1, ND1);
}

// ---------------- scatter src ids into dst-sorted order --------------------
__global__ void kc_scatter(const int* __restrict__ esrc0, const int* __restrict__ edst0,
                           const int* __restrict__ esrc1, const int* __restrict__ edst1,
                           int* __restrict__ cur0, int* __restrict__ cur1,
                           int* __restrict__ srcsort0, int* __restrict__ srcsort1) {
    int t = blockIdx.x * blockDim.x + threadIdx.x;
    if (t < NE0) {
        int pos = atomicAdd(&cur0[edst0[t]], 1);
        srcsort0[pos] = esrc0[t];
    } else if (t < NE0 + NE1) {
        int e = t - NE0;
        int pos = atomicAdd(&cur1[edst1[e]], 1);
        srcsort1[pos] = esrc1[e];
    }
}

// ---------------- layer 1 node transform (register-blocked GEMM) -----------
// tile: 64 rows x 64 cols, thread = 4x4; xt transposed [k][row] pad 68
// ht1 stored bf16 (halves k3's gather bytes)
__global__ __launch_bounds__(256) void k1_node1(
        const float* __restrict__ x, const int* __restrict__ n_id0,
        const float* __restrict__ W1, const float* __restrict__ a_src,
        const float* __restrict__ a_dst,
        unsigned short* __restrict__ ht1b, float* __restrict__ es1, float* __restrict__ ed1) {
    __shared__ float xt[64*68];
    __shared__ float Wl[64*64];
    __shared__ float asl[64], adl[64];
    int t = threadIdx.x;
    for (int i = t; i < 1024; i += 256)
        *(float4*)&Wl[i*4] = *(const float4*)&W1[i*4];
    if (t < 64) { asl[t] = a_src[t]; adl[t] = a_dst[t]; }
    int rr = t & 63;
    int q  = t >> 6;                       // k-quarter 0..3
    int row_s = blockIdx.x * 64 + rr;      // < 120000 always (1875*64)
    int bs = row_s / NS0;
    int ns = row_s - bs * NS0;
    const float* xrow = x + ((size_t)(bs * NT + n_id0[ns])) * 64;
    #pragma unroll
    for (int j = 0; j < 4; ++j) {
        int k = q * 16 + j * 4;
        float4 v = *(const float4*)&xrow[k];
        xt[(k+0)*68 + rr] = v.x;
        xt[(k+1)*68 + rr] = v.y;
        xt[(k+2)*68 + rr] = v.z;
        xt[(k+3)*68 + rr] = v.w;
    }
    __syncthreads();
    int c0 = (t & 15) * 4;
    int r0 = (t >> 4) * 4;
    float acc[4][4] = {};
    #pragma unroll 16
    for (int k = 0; k < 64; ++k) {
        float4 a = *(const float4*)&xt[k*68 + r0];
        float4 w = *(const float4*)&Wl[k*64 + c0];
        acc[0][0] = fmaf(a.x, w.x, acc[0][0]); acc[0][1] = fmaf(a.x, w.y, acc[0][1]);
        acc[0][2] = fmaf(a.x, w.z, acc[0][2]); acc[0][3] = fmaf(a.x, w.w, acc[0][3]);
        acc[1][0] = fmaf(a.y, w.x, acc[1][0]); acc[1][1] = fmaf(a.y, w.y, acc[1][1]);
        acc[1][2] = fmaf(a.y, w.z, acc[1][2]); acc[1][3] = fmaf(a.y, w.w, acc[1][3]);
        acc[2][0] = fmaf(a.z, w.x, acc[2][0]); acc[2][1] = fmaf(a.z, w.y, acc[2][1]);
        acc[2][2] = fmaf(a.z, w.z, acc[2][2]); acc[2][3] = fmaf(a.z, w.w, acc[2][3]);
        acc[3][0] = fmaf(a.w, w.x, acc[3][0]); acc[3][1] = fmaf(a.w, w.y, acc[3][1]);
        acc[3][2] = fmaf(a.w, w.z, acc[3][2]); acc[3][3] = fmaf(a.w, w.w, acc[3][3]);
    }
    float as0 = asl[c0], as1 = asl[c0+1], as2 = asl[c0+2], as3 = asl[c0+3];
    float ad0 = adl[c0], ad1 = adl[c0+1], ad2 = adl[c0+2], ad3 = adl[c0+3];
    int hh = (t & 15) >> 1;
    #pragma unroll
    for (int i = 0; i < 4; ++i) {
        int row = blockIdx.x * 64 + r0 + i;
        ushort4 ov;
        ov.x = f2bf(acc[i][0]); ov.y = f2bf(acc[i][1]);
        ov.z = f2bf(acc[i][2]); ov.w = f2bf(acc[i][3]);
        *(ushort4*)&ht1b[(size_t)row*64 + c0] = ov;
        float ps = acc[i][0]*as0 + acc[i][1]*as1 + acc[i][2]*as2 + acc[i][3]*as3;
        float pd = acc[i][0]*ad0 + acc[i][1]*ad1 + acc[i][2]*ad2 + acc[i][3]*ad3;
        ps += __shfl_xor(ps, 1);
        pd += __shfl_xor(pd, 1);
        if ((t & 1) == 0) {
            es1[row*8 + hh] = ps;
            ed1[row*8 + hh] = pd;
        }
    }
}

// ---------------- layer 1 per-dst aggregation (batch-major, bf16 gather) ---
// block = 4 dsts x 1 batch; batch-major grid keeps per-batch slice hot in L2
__global__ __launch_bounds__(256) void k3_agg1(
        const int* __restrict__ srcsort0, const int* __restrict__ off0,
        const int* __restrict__ deg0, const int* __restrict__ res0,
        const float* __restrict__ es1, const float* __restrict__ ed1,
        const unsigned short* __restrict__ ht1b, const float* __restrict__ b1,
        float* __restrict__ agg1) {
    int b = blockIdx.x / (ND0/4);
    int chunk = blockIdx.x - b * (ND0/4);
    int d = chunk * 4 + (threadIdx.x >> 6);
    int lane = threadIdx.x & 63;
    int h = lane >> 3;
    int dn = res0[d];
    float edv = ed1[(b*NS0 + dn)*8 + h];
    int start = off0[d];
    int cnt = deg0[d];
    float acc0 = 0.f, acc1 = 0.f, ws0 = 0.f, ws1 = 0.f;
    int i = 0;
    for (; i + 1 < cnt; i += 2) {
        int s0 = srcsort0[start + i];
        int s1 = srcsort0[start + i + 1];
        float e0 = es1[(b*NS0 + s0)*8 + h] + edv;
        float e1 = es1[(b*NS0 + s1)*8 + h] + edv;
        float h0 = bf2f(ht1b[((size_t)(b*NS0 + s0))*64 + lane]);
        float h1 = bf2f(ht1b[((size_t)(b*NS0 + s1))*64 + lane]);
        e0 = e0 > 0.f ? e0 : NEG * e0;
        e1 = e1 > 0.f ? e1 : NEG * e1;
        float w0 = __expf(e0), w1 = __expf(e1);
        acc0 = fmaf(w0, h0, acc0); ws0 += w0;
        acc1 = fmaf(w1, h1, acc1); ws1 += w1;
    }
    if (i < cnt) {
        int s0 = srcsort0[start + i];
        float e0 = es1[(b*NS0 + s0)*8 + h] + edv;
        float h0 = bf2f(ht1b[((size_t)(b*NS0 + s0))*64 + lane]);
        e0 = e0 > 0.f ? e0 : NEG * e0;
        float w0 = __expf(e0);
        acc0 = fmaf(w0, h0, acc0); ws0 += w0;
    }
    float acc = acc0 + acc1, wsum = ws0 + ws1;
    float out = cnt > 0 ? acc / wsum : 0.f;
    out += b1[lane];
    out = out > 0.f ? out : __expf(out) - 1.f;   // fused ELU
    agg1[((size_t)(b*ND0 + d))*64 + lane] = out;
}

// ---------------- layer 2 node transform (register-blocked GEMM) -----------
__global__ __launch_bounds__(256) void k5_node2(
        const float* __restrict__ h, const float* __restrict__ W2,
        const float* __restrict__ a_src2, const float* __restrict__ a_dst2,
        float* __restrict__ ht2, float* __restrict__ es2, float* __restrict__ ed2) {
    __shared__ float xt[64*132];
    __shared__ float Wl[64*32];
    __shared__ float as2[32], ad2[32];
    int t = threadIdx.x;
    for (int i = t; i < 512; i += 256)
        *(float4*)&Wl[i*4] = *(const float4*)&W2[i*4];
    if (t < 32) { as2[t] = a_src2[t]; ad2[t] = a_dst2[t]; }
    int rr = t & 127;
    int q  = t >> 7;
    int row_s = blockIdx.x * 128 + rr;
    bool valid = row_s < NB*ND0;
    const float* hrow = h + (size_t)row_s * 64;
    #pragma unroll
    for (int j = 0; j < 8; ++j) {
        int k = q * 32 + j * 4;
        float4 v = valid ? *(const float4*)&hrow[k] : make_float4(0.f,0.f,0.f,0.f);
        xt[(k+0)*132 + rr] = v.x;
        xt[(k+1)*132 + rr] = v.y;
        xt[(k+2)*132 + rr] = v.z;
        xt[(k+3)*132 + rr] = v.w;
    }
    __syncthreads();
    int c0 = (t & 7) * 4;
    int r0 = (t >> 3) * 4;
    float acc[4][4] = {};
    #pragma unroll 16
    for (int k = 0; k < 64; ++k) {
        float4 a = *(const float4*)&xt[k*132 + r0];
        float4 w = *(const float4*)&Wl[k*32 + c0];
        acc[0][0] = fmaf(a.x, w.x, acc[0][0]); acc[0][1] = fmaf(a.x, w.y, acc[0][1]);
        acc[0][2] = fmaf(a.x, w.z, acc[0][2]); acc[0][3] = fmaf(a.x, w.w, acc[0][3]);
        acc[1][0] = fmaf(a.y, w.x, acc[1][0]); acc[1][1] = fmaf(a.y, w.y, acc[1][1]);
        acc[1][2] = fmaf(a.y, w.z, acc[1][2]); acc[1][3] = fmaf(a.y, w.w, acc[1][3]);
        acc[2][0] = fmaf(a.z, w.x, acc[2][0]); acc[2][1] = fmaf(a.z, w.y, acc[2][1]);
        acc[2][2] = fmaf(a.z, w.z, acc[2][2]); acc[2][3] = fmaf(a.z, w.w, acc[2][3]);
        acc[3][0] = fmaf(a.w, w.x, acc[3][0]); acc[3][1] = fmaf(a.w, w.y, acc[3][1]);
        acc[3][2] = fmaf(a.w, w.z, acc[3][2]); acc[3][3] = fmaf(a.w, w.w, acc[3][3]);
    }
    float s0 = as2[c0], s1 = as2[c0+1], s2 = as2[c0+2], s3 = as2[c0+3];
    float d0 = ad2[c0], d1 = ad2[c0+1], d2 = ad2[c0+2], d3 = ad2[c0+3];
    #pragma unroll
    for (int i = 0; i < 4; ++i) {
        int row = blockIdx.x * 128 + r0 + i;
        float ps = acc[i][0]*s0 + acc[i][1]*s1 + acc[i][2]*s2 + acc[i][3]*s3;
        float pd = acc[i][0]*d0 + acc[i][1]*d1 + acc[i][2]*d2 + acc[i][3]*d3;
        ps += __shfl_xor(ps, 1); ps += __shfl_xor(ps, 2); ps += __shfl_xor(ps, 4);
        pd += __shfl_xor(pd, 1); pd += __shfl_xor(pd, 2); pd += __shfl_xor(pd, 4);
        if (row < NB*ND0) {
            *(float4*)&ht2[(size_t)row*32 + c0] =
                make_float4(acc[i][0], acc[i][1], acc[i][2], acc[i][3]);
            if ((t & 7) == 0) { es2[row] = ps; ed2[row] = pd; }
        }
    }
}

// ---------------- layer 2 per-dst aggregation (batch-major) ----------------
__global__ __launch_bounds__(256) void k7_agg2(
        const int* __restrict__ srcsort1, const int* __restrict__ off1,
        const int* __restrict__ deg1, const int* __restrict__ res1,
        const float* __restrict__ es2, const float* __restrict__ ed2,
        const float* __restrict__ ht2, const float* __restrict__ b2,
        float* __restrict__ outp) {
    int b = blockIdx.x / (ND1/4);
    int chunk = blockIdx.x - b * (ND1/4);
    int d = chunk * 4 + (threadIdx.x >> 6);
    int lane = threadIdx.x & 63;
    int grp = lane >> 5;
    int c = lane & 31;
    int dn = res1[d];
    float edv = ed2[b*ND0 + dn];
    int start = off1[d];
    int cnt = deg1[d];
    float acc = 0.f, wsum = 0.f;
    for (int i = grp; i < cnt; i += 2) {
        int s = srcsort1[start + i];
        float lg = es2[b*ND0 + s] + edv;
        lg = lg > 0.f ? lg : NEG * lg;
        float w = __expf(lg);
        float hv = ht2[((size_t)(b*ND0 + s))*32 + c];
        acc = fmaf(w, hv, acc);
        wsum += w;
    }
    acc  += __shfl_xor(acc, 32);
    wsum += __shfl_xor(wsum, 32);
    float out = cnt > 0 ? acc / wsum : 0.f;
    out += b2[c];
    if (grp == 0) outp[((size_t)(b*ND1 + d))*32 + c] = out;
}

extern "C" void kernel_launch(void* const* d_in, const int* in_sizes, int n_in,
                              void* d_out, int out_size, void* d_ws, size_t ws_size,
                              hipStream_t stream) {
    const float* x        = (const float*)d_in[0];
    const int*   n_id0    = (const int*)d_in[1];
    const int*   res0     = (const int*)d_in[2];
    const int*   esrc0    = (const int*)d_in[3];
    const int*   edst0    = (const int*)d_in[4];
    const int*   res1     = (const int*)d_in[5];
    const int*   esrc1    = (const int*)d_in[6];
    const int*   edst1    = (const int*)d_in[7];
    const float* W1       = (const float*)d_in[8];
    const float* a_src1   = (const float*)d_in[9];
    const float* a_dst1   = (const float*)d_in[10];
    const float* b1       = (const float*)d_in[11];
    const float* W2       = (const float*)d_in[12];
    const float* a_src2   = (const float*)d_in[13];
    const float* a_dst2   = (const float*)d_in[14];
    const float* b2       = (const float*)d_in[15];
    float* outp = (float*)d_out;

    char* base = (char*)d_ws;
    unsigned short* ht1b = (unsigned short*)base;            // 120000*64*2  = 15,360,000 B
    float* es1  = (float*)(base + 15360000);                 // 960,000 f
    float* ed1  = es1 + 960000;                              // 960,000 f
    float* agg1 = ed1 + 960000;                              // 3,840,000 f
    float* ht2  = agg1 + 3840000;                            // 1,920,000 f
    float* es2  = ht2 + 1920000;                             // 60,000 f
    float* ed2  = es2 + 60000;                               // 60,000 f
    int* deg0     = (int*)(ed2 + 60000);                     // 15000
    int* off0     = deg0 + ND0;
    int* cur0     = off0 + ND0;
    int* deg1     = cur0 + ND0;
    int* off1     = deg1 + ND1;
    int* cur1     = off1 + ND1;
    int* srcsort0 = cur1 + ND1;                              // 360000
    int* srcsort1 = srcsort0 + NE0;                          // 180000
    // total ~49.2 MB

    kz_zero<<<(ND0 + 255)/256, 256, 0, stream>>>(deg0, deg1);
    kh_hist<<<(NE0 + NE1 + 255)/256, 256, 0, stream>>>(edst0, edst1, deg0, deg1);
    ks_scan<<<2, 1024, 0, stream>>>(deg0, off0, cur0, deg1, off1, cur1);
    kc_scatter<<<(NE0 + NE1 + 255)/256, 256, 0, stream>>>(esrc0, edst0, esrc1, edst1,
                                                          cur0, cur1, srcsort0, srcsort1);
    k1_node1<<<(NB*NS0)/64, 256, 0, stream>>>(x, n_id0, W1, a_src1, a_dst1, ht1b, es1, ed1);
    k3_agg1<<<NB*(ND0/4), 256, 0, stream>>>(srcsort0, off0, deg0, res0, es1, ed1, ht1b, b1, agg1);
    k5_node2<<<(NB*ND0 + 127)/128, 256, 0, stream>>>(agg1, W2, a_src2, a_dst2, ht2, es2, ed2);
    k7_agg2<<<NB*(ND1/4), 256, 0, stream>>>(srcsort1, off1, deg1, res1, es2, ed2, ht2, b2, outp);
}

// Round 6
// 282.622 us; speedup vs baseline: 1.1788x; 1.1788x over previous
//
#include <hip/hip_runtime.h>

#define NB 4
#define NT 40000
#define NS0 30000
#define ND0 15000
#define NE0 360000
#define ND1 7500
#define NE1 180000
#define NEG 0.2f

__device__ __forceinline__ unsigned short f2bf(float f) {
    unsigned u = __float_as_uint(f);
    u += 0x7FFF + ((u >> 16) & 1);          // round-to-nearest-even
    return (unsigned short)(u >> 16);
}
__device__ __forceinline__ float bf2f(unsigned short s) {
    return __uint_as_float((unsigned)s << 16);
}

// ---------------- zero degree histograms -----------------------------------
__global__ void kz_zero(int* __restrict__ deg0, int* __restrict__ deg1) {
    int t = blockIdx.x * blockDim.x + threadIdx.x;
    if (t < ND0) deg0[t] = 0;
    if (t < ND1) deg1[t] = 0;
}

// ---------------- histogram of edge destinations ---------------------------
__global__ void kh_hist(const int* __restrict__ edst0, const int* __restrict__ edst1,
                        int* __restrict__ deg0, int* __restrict__ deg1) {
    int t = blockIdx.x * blockDim.x + threadIdx.x;
    if (t < NE0) atomicAdd(&deg0[edst0[t]], 1);
    else if (t < NE0 + NE1) atomicAdd(&deg1[edst1[t - NE0]], 1);
}

// ---------------- exclusive scan (one block per layer) ---------------------
__device__ void scan_block(const int* __restrict__ deg, int* __restrict__ off,
                           int* __restrict__ cur, int n) {
    __shared__ int s[1024];
    int t = threadIdx.x;
    int chunk = (n + 1023) / 1024;
    int base = t * chunk;
    int mysum = 0;
    for (int i = 0; i < chunk; ++i) {
        int idx = base + i;
        if (idx < n) mysum += deg[idx];
    }
    s[t] = mysum;
    __syncthreads();
    for (int o = 1; o < 1024; o <<= 1) {
        int v = (t >= o) ? s[t - o] : 0;
        __syncthreads();
        s[t] += v;
        __syncthreads();
    }
    int run = s[t] - mysum;   // exclusive prefix of my chunk
    for (int i = 0; i < chunk; ++i) {
        int idx = base + i;
        if (idx < n) {
            off[idx] = run;
            cur[idx] = run;
            run += deg[idx];
        }
    }
}

__global__ void ks_scan(const int* __restrict__ deg0, int* __restrict__ off0, int* __restrict__ cur0,
                        const int* __restrict__ deg1, int* __restrict__ off1, int* __restrict__ cur1) {
    if (blockIdx.x == 0) scan_block(deg0, off0, cur0, ND0);
    else                 scan_block(deg1, off1, cur1, ND1);
}

// ---------------- scatter src ids into dst-sorted order --------------------
__global__ void kc_scatter(const int* __restrict__ esrc0, const int* __restrict__ edst0,
                           const int* __restrict__ esrc1, const int* __restrict__ edst1,
                           int* __restrict__ cur0, int* __restrict__ cur1,
                           int* __restrict__ srcsort0, int* __restrict__ srcsort1) {
    int t = blockIdx.x * blockDim.x + threadIdx.x;
    if (t < NE0) {
        int pos = atomicAdd(&cur0[edst0[t]], 1);
        srcsort0[pos] = esrc0[t];
    } else if (t < NE0 + NE1) {
        int e = t - NE0;
        int pos = atomicAdd(&cur1[edst1[e]], 1);
        srcsort1[pos] = esrc1[e];
    }
}

// ---------------- layer 1 node transform (register-blocked GEMM) -----------
// tile: 64 rows x 64 cols, thread = 4x4; xt transposed [k][row] pad 68
// ht1 stored bf16 (halves k3's gather bytes)
__global__ __launch_bounds__(256) void k1_node1(
        const float* __restrict__ x, const int* __restrict__ n_id0,
        const float* __restrict__ W1, const float* __restrict__ a_src,
        const float* __restrict__ a_dst,
        unsigned short* __restrict__ ht1b, float* __restrict__ es1, float* __restrict__ ed1) {
    __shared__ float xt[64*68];
    __shared__ float Wl[64*64];
    __shared__ float asl[64], adl[64];
    int t = threadIdx.x;
    for (int i = t; i < 1024; i += 256)
        *(float4*)&Wl[i*4] = *(const float4*)&W1[i*4];
    if (t < 64) { asl[t] = a_src[t]; adl[t] = a_dst[t]; }
    int rr = t & 63;
    int q  = t >> 6;                       // k-quarter 0..3
    int row_s = blockIdx.x * 64 + rr;      // < 120000 always (1875*64)
    int bs = row_s / NS0;
    int ns = row_s - bs * NS0;
    const float* xrow = x + ((size_t)(bs * NT + n_id0[ns])) * 64;
    #pragma unroll
    for (int j = 0; j < 4; ++j) {
        int k = q * 16 + j * 4;
        float4 v = *(const float4*)&xrow[k];
        xt[(k+0)*68 + rr] = v.x;
        xt[(k+1)*68 + rr] = v.y;
        xt[(k+2)*68 + rr] = v.z;
        xt[(k+3)*68 + rr] = v.w;
    }
    __syncthreads();
    int c0 = (t & 15) * 4;
    int r0 = (t >> 4) * 4;
    float acc[4][4] = {};
    #pragma unroll 16
    for (int k = 0; k < 64; ++k) {
        float4 a = *(const float4*)&xt[k*68 + r0];
        float4 w = *(const float4*)&Wl[k*64 + c0];
        acc[0][0] = fmaf(a.x, w.x, acc[0][0]); acc[0][1] = fmaf(a.x, w.y, acc[0][1]);
        acc[0][2] = fmaf(a.x, w.z, acc[0][2]); acc[0][3] = fmaf(a.x, w.w, acc[0][3]);
        acc[1][0] = fmaf(a.y, w.x, acc[1][0]); acc[1][1] = fmaf(a.y, w.y, acc[1][1]);
        acc[1][2] = fmaf(a.y, w.z, acc[1][2]); acc[1][3] = fmaf(a.y, w.w, acc[1][3]);
        acc[2][0] = fmaf(a.z, w.x, acc[2][0]); acc[2][1] = fmaf(a.z, w.y, acc[2][1]);
        acc[2][2] = fmaf(a.z, w.z, acc[2][2]); acc[2][3] = fmaf(a.z, w.w, acc[2][3]);
        acc[3][0] = fmaf(a.w, w.x, acc[3][0]); acc[3][1] = fmaf(a.w, w.y, acc[3][1]);
        acc[3][2] = fmaf(a.w, w.z, acc[3][2]); acc[3][3] = fmaf(a.w, w.w, acc[3][3]);
    }
    float as0 = asl[c0], as1 = asl[c0+1], as2 = asl[c0+2], as3 = asl[c0+3];
    float ad0 = adl[c0], ad1 = adl[c0+1], ad2 = adl[c0+2], ad3 = adl[c0+3];
    int hh = (t & 15) >> 1;
    #pragma unroll
    for (int i = 0; i < 4; ++i) {
        int row = blockIdx.x * 64 + r0 + i;
        ushort4 ov;
        ov.x = f2bf(acc[i][0]); ov.y = f2bf(acc[i][1]);
        ov.z = f2bf(acc[i][2]); ov.w = f2bf(acc[i][3]);
        *(ushort4*)&ht1b[(size_t)row*64 + c0] = ov;
        float ps = acc[i][0]*as0 + acc[i][1]*as1 + acc[i][2]*as2 + acc[i][3]*as3;
        float pd = acc[i][0]*ad0 + acc[i][1]*ad1 + acc[i][2]*ad2 + acc[i][3]*ad3;
        ps += __shfl_xor(ps, 1);
        pd += __shfl_xor(pd, 1);
        if ((t & 1) == 0) {
            es1[row*8 + hh] = ps;
            ed1[row*8 + hh] = pd;
        }
    }
}

// ---------------- layer 1 per-dst aggregation (vectorized edge-parallel) ---
// block = 1 dst x 4 batches (shared edge list, equal loop lengths).
// wave: 4 x 16-lane groups, group = 1 edge, lane = 4 channels (ushort4 = 8B).
__global__ __launch_bounds__(256) void k3_agg1(
        const int* __restrict__ srcsort0, const int* __restrict__ off0,
        const int* __restrict__ deg0, const int* __restrict__ res0,
        const float* __restrict__ es1, const float* __restrict__ ed1,
        const unsigned short* __restrict__ ht1b, const float* __restrict__ b1,
        float* __restrict__ agg1) {
    int d = blockIdx.x;
    int b = threadIdx.x >> 6;
    int lane = threadIdx.x & 63;
    int grp = lane >> 4;                   // edge slot 0..3
    int c = lane & 15;                     // channel quad: channels 4c..4c+3
    int h = c >> 1;                        // head of this channel quad
    int dn = res0[d];
    float edv = ed1[(b*NS0 + dn)*8 + h];
    int start = off0[d];
    int cnt = deg0[d];
    float ax = 0.f, ay = 0.f, az = 0.f, aw = 0.f, wsum = 0.f;
    for (int i = grp; i < cnt; i += 4) {
        int s = srcsort0[start + i];
        float e = es1[(b*NS0 + s)*8 + h] + edv;
        ushort4 hv = *(const ushort4*)&ht1b[((size_t)(b*NS0 + s))*64 + c*4];
        e = e > 0.f ? e : NEG * e;
        float w = __expf(e);
        ax = fmaf(w, bf2f(hv.x), ax);
        ay = fmaf(w, bf2f(hv.y), ay);
        az = fmaf(w, bf2f(hv.z), az);
        aw = fmaf(w, bf2f(hv.w), aw);
        wsum += w;
    }
    // combine the 4 edge groups (lanes c, c+16, c+32, c+48 hold same channels)
    ax += __shfl_xor(ax, 16); ax += __shfl_xor(ax, 32);
    ay += __shfl_xor(ay, 16); ay += __shfl_xor(ay, 32);
    az += __shfl_xor(az, 16); az += __shfl_xor(az, 32);
    aw += __shfl_xor(aw, 16); aw += __shfl_xor(aw, 32);
    wsum += __shfl_xor(wsum, 16); wsum += __shfl_xor(wsum, 32);
    if (grp == 0) {
        float inv = cnt > 0 ? 1.f / wsum : 0.f;
        float4 bb = *(const float4*)&b1[c*4];
        float4 o;
        o.x = ax*inv + bb.x; o.y = ay*inv + bb.y;
        o.z = az*inv + bb.z; o.w = aw*inv + bb.w;
        o.x = o.x > 0.f ? o.x : __expf(o.x) - 1.f;
        o.y = o.y > 0.f ? o.y : __expf(o.y) - 1.f;
        o.z = o.z > 0.f ? o.z : __expf(o.z) - 1.f;
        o.w = o.w > 0.f ? o.w : __expf(o.w) - 1.f;
        *(float4*)&agg1[((size_t)(b*ND0 + d))*64 + c*4] = o;
    }
}

// ---------------- layer 2 node transform (register-blocked GEMM) -----------
__global__ __launch_bounds__(256) void k5_node2(
        const float* __restrict__ h, const float* __restrict__ W2,
        const float* __restrict__ a_src2, const float* __restrict__ a_dst2,
        float* __restrict__ ht2, float* __restrict__ es2, float* __restrict__ ed2) {
    __shared__ float xt[64*132];
    __shared__ float Wl[64*32];
    __shared__ float as2[32], ad2[32];
    int t = threadIdx.x;
    for (int i = t; i < 512; i += 256)
        *(float4*)&Wl[i*4] = *(const float4*)&W2[i*4];
    if (t < 32) { as2[t] = a_src2[t]; ad2[t] = a_dst2[t]; }
    int rr = t & 127;
    int q  = t >> 7;
    int row_s = blockIdx.x * 128 + rr;
    bool valid = row_s < NB*ND0;
    const float* hrow = h + (size_t)row_s * 64;
    #pragma unroll
    for (int j = 0; j < 8; ++j) {
        int k = q * 32 + j * 4;
        float4 v = valid ? *(const float4*)&hrow[k] : make_float4(0.f,0.f,0.f,0.f);
        xt[(k+0)*132 + rr] = v.x;
        xt[(k+1)*132 + rr] = v.y;
        xt[(k+2)*132 + rr] = v.z;
        xt[(k+3)*132 + rr] = v.w;
    }
    __syncthreads();
    int c0 = (t & 7) * 4;
    int r0 = (t >> 3) * 4;
    float acc[4][4] = {};
    #pragma unroll 16
    for (int k = 0; k < 64; ++k) {
        float4 a = *(const float4*)&xt[k*132 + r0];
        float4 w = *(const float4*)&Wl[k*32 + c0];
        acc[0][0] = fmaf(a.x, w.x, acc[0][0]); acc[0][1] = fmaf(a.x, w.y, acc[0][1]);
        acc[0][2] = fmaf(a.x, w.z, acc[0][2]); acc[0][3] = fmaf(a.x, w.w, acc[0][3]);
        acc[1][0] = fmaf(a.y, w.x, acc[1][0]); acc[1][1] = fmaf(a.y, w.y, acc[1][1]);
        acc[1][2] = fmaf(a.y, w.z, acc[1][2]); acc[1][3] = fmaf(a.y, w.w, acc[1][3]);
        acc[2][0] = fmaf(a.z, w.x, acc[2][0]); acc[2][1] = fmaf(a.z, w.y, acc[2][1]);
        acc[2][2] = fmaf(a.z, w.z, acc[2][2]); acc[2][3] = fmaf(a.z, w.w, acc[2][3]);
        acc[3][0] = fmaf(a.w, w.x, acc[3][0]); acc[3][1] = fmaf(a.w, w.y, acc[3][1]);
        acc[3][2] = fmaf(a.w, w.z, acc[3][2]); acc[3][3] = fmaf(a.w, w.w, acc[3][3]);
    }
    float s0 = as2[c0], s1 = as2[c0+1], s2 = as2[c0+2], s3 = as2[c0+3];
    float d0 = ad2[c0], d1 = ad2[c0+1], d2 = ad2[c0+2], d3 = ad2[c0+3];
    #pragma unroll
    for (int i = 0; i < 4; ++i) {
        int row = blockIdx.x * 128 + r0 + i;
        float ps = acc[i][0]*s0 + acc[i][1]*s1 + acc[i][2]*s2 + acc[i][3]*s3;
        float pd = acc[i][0]*d0 + acc[i][1]*d1 + acc[i][2]*d2 + acc[i][3]*d3;
        ps += __shfl_xor(ps, 1); ps += __shfl_xor(ps, 2); ps += __shfl_xor(ps, 4);
        pd += __shfl_xor(pd, 1); pd += __shfl_xor(pd, 2); pd += __shfl_xor(pd, 4);
        if (row < NB*ND0) {
            *(float4*)&ht2[(size_t)row*32 + c0] =
                make_float4(acc[i][0], acc[i][1], acc[i][2], acc[i][3]);
            if ((t & 7) == 0) { es2[row] = ps; ed2[row] = pd; }
        }
    }
}

// ---------------- layer 2 per-dst aggregation (vectorized edge-parallel) ---
// block = 1 dst x 4 batches; wave: 8 x 8-lane groups, group = 1 edge,
// lane = 4 channels (float4).
__global__ __launch_bounds__(256) void k7_agg2(
        const int* __restrict__ srcsort1, const int* __restrict__ off1,
        const int* __restrict__ deg1, const int* __restrict__ res1,
        const float* __restrict__ es2, const float* __restrict__ ed2,
        const float* __restrict__ ht2, const float* __restrict__ b2,
        float* __restrict__ outp) {
    int d = blockIdx.x;
    int b = threadIdx.x >> 6;
    int lane = threadIdx.x & 63;
    int grp = lane >> 3;                   // edge slot 0..7
    int c = lane & 7;                      // channel quad: channels 4c..4c+3
    int dn = res1[d];
    float edv = ed2[b*ND0 + dn];
    int start = off1[d];
    int cnt = deg1[d];
    float ax = 0.f, ay = 0.f, az = 0.f, aw = 0.f, wsum = 0.f;
    for (int i = grp; i < cnt; i += 8) {
        int s = srcsort1[start + i];
        float lg = es2[b*ND0 + s] + edv;
        float4 hv = *(const float4*)&ht2[((size_t)(b*ND0 + s))*32 + c*4];
        lg = lg > 0.f ? lg : NEG * lg;
        float w = __expf(lg);
        ax = fmaf(w, hv.x, ax);
        ay = fmaf(w, hv.y, ay);
        az = fmaf(w, hv.z, az);
        aw = fmaf(w, hv.w, aw);
        wsum += w;
    }
    ax += __shfl_xor(ax, 8); ax += __shfl_xor(ax, 16); ax += __shfl_xor(ax, 32);
    ay += __shfl_xor(ay, 8); ay += __shfl_xor(ay, 16); ay += __shfl_xor(ay, 32);
    az += __shfl_xor(az, 8); az += __shfl_xor(az, 16); az += __shfl_xor(az, 32);
    aw += __shfl_xor(aw, 8); aw += __shfl_xor(aw, 16); aw += __shfl_xor(aw, 32);
    wsum += __shfl_xor(wsum, 8); wsum += __shfl_xor(wsum, 16); wsum += __shfl_xor(wsum, 32);
    if (grp == 0) {
        float inv = cnt > 0 ? 1.f / wsum : 0.f;
        float4 bb = *(const float4*)&b2[c*4];
        float4 o;
        o.x = ax*inv + bb.x; o.y = ay*inv + bb.y;
        o.z = az*inv + bb.z; o.w = aw*inv + bb.w;
        *(float4*)&outp[((size_t)(b*ND1 + d))*32 + c*4] = o;
    }
}

extern "C" void kernel_launch(void* const* d_in, const int* in_sizes, int n_in,
                              void* d_out, int out_size, void* d_ws, size_t ws_size,
                              hipStream_t stream) {
    const float* x        = (const float*)d_in[0];
    const int*   n_id0    = (const int*)d_in[1];
    const int*   res0     = (const int*)d_in[2];
    const int*   esrc0    = (const int*)d_in[3];
    const int*   edst0    = (const int*)d_in[4];
    const int*   res1     = (const int*)d_in[5];
    const int*   esrc1    = (const int*)d_in[6];
    const int*   edst1    = (const int*)d_in[7];
    const float* W1       = (const float*)d_in[8];
    const float* a_src1   = (const float*)d_in[9];
    const float* a_dst1   = (const float*)d_in[10];
    const float* b1       = (const float*)d_in[11];
    const float* W2       = (const float*)d_in[12];
    const float* a_src2   = (const float*)d_in[13];
    const float* a_dst2   = (const float*)d_in[14];
    const float* b2       = (const float*)d_in[15];
    float* outp = (float*)d_out;

    char* base = (char*)d_ws;
    unsigned short* ht1b = (unsigned short*)base;            // 120000*64*2  = 15,360,000 B
    float* es1  = (float*)(base + 15360000);                 // 960,000 f
    float* ed1  = es1 + 960000;                              // 960,000 f
    float* agg1 = ed1 + 960000;                              // 3,840,000 f
    float* ht2  = agg1 + 3840000;                            // 1,920,000 f
    float* es2  = ht2 + 1920000;                             // 60,000 f
    float* ed2  = es2 + 60000;                               // 60,000 f
    int* deg0     = (int*)(ed2 + 60000);                     // 15000
    int* off0     = deg0 + ND0;
    int* cur0     = off0 + ND0;
    int* deg1     = cur0 + ND0;
    int* off1     = deg1 + ND1;
    int* cur1     = off1 + ND1;
    int* srcsort0 = cur1 + ND1;                              // 360000
    int* srcsort1 = srcsort0 + NE0;                          // 180000
    // total ~49.2 MB

    kz_zero<<<(ND0 + 255)/256, 256, 0, stream>>>(deg0, deg1);
    kh_hist<<<(NE0 + NE1 + 255)/256, 256, 0, stream>>>(edst0, edst1, deg0, deg1);
    ks_scan<<<2, 1024, 0, stream>>>(deg0, off0, cur0, deg1, off1, cur1);
    kc_scatter<<<(NE0 + NE1 + 255)/256, 256, 0, stream>>>(esrc0, edst0, esrc1, edst1,
                                                          cur0, cur1, srcsort0, srcsort1);
    k1_node1<<<(NB*NS0)/64, 256, 0, stream>>>(x, n_id0, W1, a_src1, a_dst1, ht1b, es1, ed1);
    k3_agg1<<<ND0, 256, 0, stream>>>(srcsort0, off0, deg0, res0, es1, ed1, ht1b, b1, agg1);
    k5_node2<<<(NB*ND0 + 127)/128, 256, 0, stream>>>(agg1, W2, a_src2, a_dst2, ht2, es2, ed2);
    k7_agg2<<<ND1, 256, 0, stream>>>(srcsort1, off1, deg1, res1, es2, ed2, ht2, b2, outp);
}

// Round 7
// 278.494 us; speedup vs baseline: 1.1963x; 1.0148x over previous
//
#include <hip/hip_runtime.h>

#define NB 4
#define NT 40000
#define NS0 30000
#define ND0 15000
#define NE0 360000
#define ND1 7500
#define NE1 180000
#define NEG 0.2f

__device__ __forceinline__ unsigned short f2bf(float f) {
    unsigned u = __float_as_uint(f);
    u += 0x7FFF + ((u >> 16) & 1);          // round-to-nearest-even
    return (unsigned short)(u >> 16);
}
__device__ __forceinline__ float bf2f(unsigned short s) {
    return __uint_as_float((unsigned)s << 16);
}

// ---------------- zero degree histograms -----------------------------------
__global__ void kz_zero(int* __restrict__ deg0, int* __restrict__ deg1) {
    int t = blockIdx.x * blockDim.x + threadIdx.x;
    if (t < ND0) deg0[t] = 0;
    if (t < ND1) deg1[t] = 0;
}

// ---------------- histogram of edge destinations ---------------------------
__global__ void kh_hist(const int* __restrict__ edst0, const int* __restrict__ edst1,
                        int* __restrict__ deg0, int* __restrict__ deg1) {
    int t = blockIdx.x * blockDim.x + threadIdx.x;
    if (t < NE0) atomicAdd(&deg0[edst0[t]], 1);
    else if (t < NE0 + NE1) atomicAdd(&deg1[edst1[t - NE0]], 1);
}

// ---------------- exclusive scan (one block per layer) ---------------------
__device__ void scan_block(const int* __restrict__ deg, int* __restrict__ off,
                           int* __restrict__ cur, int n) {
    __shared__ int s[1024];
    int t = threadIdx.x;
    int chunk = (n + 1023) / 1024;
    int base = t * chunk;
    int mysum = 0;
    for (int i = 0; i < chunk; ++i) {
        int idx = base + i;
        if (idx < n) mysum += deg[idx];
    }
    s[t] = mysum;
    __syncthreads();
    for (int o = 1; o < 1024; o <<= 1) {
        int v = (t >= o) ? s[t - o] : 0;
        __syncthreads();
        s[t] += v;
        __syncthreads();
    }
    int run = s[t] - mysum;   // exclusive prefix of my chunk
    for (int i = 0; i < chunk; ++i) {
        int idx = base + i;
        if (idx < n) {
            off[idx] = run;
            cur[idx] = run;
            run += deg[idx];
        }
    }
}

__global__ void ks_scan(const int* __restrict__ deg0, int* __restrict__ off0, int* __restrict__ cur0,
                        const int* __restrict__ deg1, int* __restrict__ off1, int* __restrict__ cur1) {
    if (blockIdx.x == 0) scan_block(deg0, off0, cur0, ND0);
    else                 scan_block(deg1, off1, cur1, ND1);
}

// ---------------- scatter src ids into dst-sorted order --------------------
__global__ void kc_scatter(const int* __restrict__ esrc0, const int* __restrict__ edst0,
                           const int* __restrict__ esrc1, const int* __restrict__ edst1,
                           int* __restrict__ cur0, int* __restrict__ cur1,
                           int* __restrict__ srcsort0, int* __restrict__ srcsort1) {
    int t = blockIdx.x * blockDim.x + threadIdx.x;
    if (t < NE0) {
        int pos = atomicAdd(&cur0[edst0[t]], 1);
        srcsort0[pos] = esrc0[t];
    } else if (t < NE0 + NE1) {
        int e = t - NE0;
        int pos = atomicAdd(&cur1[edst1[e]], 1);
        srcsort1[pos] = esrc1[e];
    }
}

// ---------------- layer 1 node transform (register-blocked GEMM) -----------
// tile: 64 rows x 64 cols, thread = 4x4; xt transposed [k][row] pad 68
// ht1 stored bf16 (halves k3's gather bytes)
__global__ __launch_bounds__(256) void k1_node1(
        const float* __restrict__ x, const int* __restrict__ n_id0,
        const float* __restrict__ W1, const float* __restrict__ a_src,
        const float* __restrict__ a_dst,
        unsigned short* __restrict__ ht1b, float* __restrict__ es1, float* __restrict__ ed1) {
    __shared__ float xt[64*68];
    __shared__ float Wl[64*64];
    __shared__ float asl[64], adl[64];
    int t = threadIdx.x;
    for (int i = t; i < 1024; i += 256)
        *(float4*)&Wl[i*4] = *(const float4*)&W1[i*4];
    if (t < 64) { asl[t] = a_src[t]; adl[t] = a_dst[t]; }
    int rr = t & 63;
    int q  = t >> 6;                       // k-quarter 0..3
    int row_s = blockIdx.x * 64 + rr;      // < 120000 always (1875*64)
    int bs = row_s / NS0;
    int ns = row_s - bs * NS0;
    const float* xrow = x + ((size_t)(bs * NT + n_id0[ns])) * 64;
    #pragma unroll
    for (int j = 0; j < 4; ++j) {
        int k = q * 16 + j * 4;
        float4 v = *(const float4*)&xrow[k];
        xt[(k+0)*68 + rr] = v.x;
        xt[(k+1)*68 + rr] = v.y;
        xt[(k+2)*68 + rr] = v.z;
        xt[(k+3)*68 + rr] = v.w;
    }
    __syncthreads();
    int c0 = (t & 15) * 4;
    int r0 = (t >> 4) * 4;
    float acc[4][4] = {};
    #pragma unroll 16
    for (int k = 0; k < 64; ++k) {
        float4 a = *(const float4*)&xt[k*68 + r0];
        float4 w = *(const float4*)&Wl[k*64 + c0];
        acc[0][0] = fmaf(a.x, w.x, acc[0][0]); acc[0][1] = fmaf(a.x, w.y, acc[0][1]);
        acc[0][2] = fmaf(a.x, w.z, acc[0][2]); acc[0][3] = fmaf(a.x, w.w, acc[0][3]);
        acc[1][0] = fmaf(a.y, w.x, acc[1][0]); acc[1][1] = fmaf(a.y, w.y, acc[1][1]);
        acc[1][2] = fmaf(a.y, w.z, acc[1][2]); acc[1][3] = fmaf(a.y, w.w, acc[1][3]);
        acc[2][0] = fmaf(a.z, w.x, acc[2][0]); acc[2][1] = fmaf(a.z, w.y, acc[2][1]);
        acc[2][2] = fmaf(a.z, w.z, acc[2][2]); acc[2][3] = fmaf(a.z, w.w, acc[2][3]);
        acc[3][0] = fmaf(a.w, w.x, acc[3][0]); acc[3][1] = fmaf(a.w, w.y, acc[3][1]);
        acc[3][2] = fmaf(a.w, w.z, acc[3][2]); acc[3][3] = fmaf(a.w, w.w, acc[3][3]);
    }
    float as0 = asl[c0], as1 = asl[c0+1], as2 = asl[c0+2], as3 = asl[c0+3];
    float ad0 = adl[c0], ad1 = adl[c0+1], ad2 = adl[c0+2], ad3 = adl[c0+3];
    int hh = (t & 15) >> 1;
    #pragma unroll
    for (int i = 0; i < 4; ++i) {
        int row = blockIdx.x * 64 + r0 + i;
        ushort4 ov;
        ov.x = f2bf(acc[i][0]); ov.y = f2bf(acc[i][1]);
        ov.z = f2bf(acc[i][2]); ov.w = f2bf(acc[i][3]);
        *(ushort4*)&ht1b[(size_t)row*64 + c0] = ov;
        float ps = acc[i][0]*as0 + acc[i][1]*as1 + acc[i][2]*as2 + acc[i][3]*as3;
        float pd = acc[i][0]*ad0 + acc[i][1]*ad1 + acc[i][2]*ad2 + acc[i][3]*ad3;
        ps += __shfl_xor(ps, 1);
        pd += __shfl_xor(pd, 1);
        if ((t & 1) == 0) {
            es1[row*8 + hh] = ps;
            ed1[row*8 + hh] = pd;
        }
    }
}

// ---------------- layer 1 per-dst aggregation ------------------------------
// batch-major blocks (4 dsts x 1 batch) keep the per-batch ht1b/es1 slice
// (~4.8 MB) hot in each XCD's L2; wave keeps R6's vectorized structure:
// 4 x 16-lane edge groups, lane = 4 channels (ushort4 = 8B).
__global__ __launch_bounds__(256) void k3_agg1(
        const int* __restrict__ srcsort0, const int* __restrict__ off0,
        const int* __restrict__ deg0, const int* __restrict__ res0,
        const float* __restrict__ es1, const float* __restrict__ ed1,
        const unsigned short* __restrict__ ht1b, const float* __restrict__ b1,
        float* __restrict__ agg1) {
    int b = blockIdx.x / (ND0/4);
    int chunk = blockIdx.x - b * (ND0/4);
    int d = chunk * 4 + (threadIdx.x >> 6);
    int lane = threadIdx.x & 63;
    int grp = lane >> 4;                   // edge slot 0..3
    int c = lane & 15;                     // channel quad: channels 4c..4c+3
    int h = c >> 1;                        // head of this channel quad
    int dn = res0[d];
    float edv = ed1[(b*NS0 + dn)*8 + h];
    int start = off0[d];
    int cnt = deg0[d];
    float ax = 0.f, ay = 0.f, az = 0.f, aw = 0.f, wsum = 0.f;
    for (int i = grp; i < cnt; i += 4) {
        int s = srcsort0[start + i];
        float e = es1[(b*NS0 + s)*8 + h] + edv;
        ushort4 hv = *(const ushort4*)&ht1b[((size_t)(b*NS0 + s))*64 + c*4];
        e = e > 0.f ? e : NEG * e;
        float w = __expf(e);
        ax = fmaf(w, bf2f(hv.x), ax);
        ay = fmaf(w, bf2f(hv.y), ay);
        az = fmaf(w, bf2f(hv.z), az);
        aw = fmaf(w, bf2f(hv.w), aw);
        wsum += w;
    }
    // combine the 4 edge groups (lanes c, c+16, c+32, c+48 hold same channels)
    ax += __shfl_xor(ax, 16); ax += __shfl_xor(ax, 32);
    ay += __shfl_xor(ay, 16); ay += __shfl_xor(ay, 32);
    az += __shfl_xor(az, 16); az += __shfl_xor(az, 32);
    aw += __shfl_xor(aw, 16); aw += __shfl_xor(aw, 32);
    wsum += __shfl_xor(wsum, 16); wsum += __shfl_xor(wsum, 32);
    if (grp == 0) {
        float inv = cnt > 0 ? 1.f / wsum : 0.f;
        float4 bb = *(const float4*)&b1[c*4];
        float4 o;
        o.x = ax*inv + bb.x; o.y = ay*inv + bb.y;
        o.z = az*inv + bb.z; o.w = aw*inv + bb.w;
        o.x = o.x > 0.f ? o.x : __expf(o.x) - 1.f;
        o.y = o.y > 0.f ? o.y : __expf(o.y) - 1.f;
        o.z = o.z > 0.f ? o.z : __expf(o.z) - 1.f;
        o.w = o.w > 0.f ? o.w : __expf(o.w) - 1.f;
        *(float4*)&agg1[((size_t)(b*ND0 + d))*64 + c*4] = o;
    }
}

// ---------------- layer 2 node transform (register-blocked GEMM) -----------
__global__ __launch_bounds__(256) void k5_node2(
        const float* __restrict__ h, const float* __restrict__ W2,
        const float* __restrict__ a_src2, const float* __restrict__ a_dst2,
        float* __restrict__ ht2, float* __restrict__ es2, float* __restrict__ ed2) {
    __shared__ float xt[64*132];
    __shared__ float Wl[64*32];
    __shared__ float as2[32], ad2[32];
    int t = threadIdx.x;
    for (int i = t; i < 512; i += 256)
        *(float4*)&Wl[i*4] = *(const float4*)&W2[i*4];
    if (t < 32) { as2[t] = a_src2[t]; ad2[t] = a_dst2[t]; }
    int rr = t & 127;
    int q  = t >> 7;
    int row_s = blockIdx.x * 128 + rr;
    bool valid = row_s < NB*ND0;
    const float* hrow = h + (size_t)row_s * 64;
    #pragma unroll
    for (int j = 0; j < 8; ++j) {
        int k = q * 32 + j * 4;
        float4 v = valid ? *(const float4*)&hrow[k] : make_float4(0.f,0.f,0.f,0.f);
        xt[(k+0)*132 + rr] = v.x;
        xt[(k+1)*132 + rr] = v.y;
        xt[(k+2)*132 + rr] = v.z;
        xt[(k+3)*132 + rr] = v.w;
    }
    __syncthreads();
    int c0 = (t & 7) * 4;
    int r0 = (t >> 3) * 4;
    float acc[4][4] = {};
    #pragma unroll 16
    for (int k = 0; k < 64; ++k) {
        float4 a = *(const float4*)&xt[k*132 + r0];
        float4 w = *(const float4*)&Wl[k*32 + c0];
        acc[0][0] = fmaf(a.x, w.x, acc[0][0]); acc[0][1] = fmaf(a.x, w.y, acc[0][1]);
        acc[0][2] = fmaf(a.x, w.z, acc[0][2]); acc[0][3] = fmaf(a.x, w.w, acc[0][3]);
        acc[1][0] = fmaf(a.y, w.x, acc[1][0]); acc[1][1] = fmaf(a.y, w.y, acc[1][1]);
        acc[1][2] = fmaf(a.y, w.z, acc[1][2]); acc[1][3] = fmaf(a.y, w.w, acc[1][3]);
        acc[2][0] = fmaf(a.z, w.x, acc[2][0]); acc[2][1] = fmaf(a.z, w.y, acc[2][1]);
        acc[2][2] = fmaf(a.z, w.z, acc[2][2]); acc[2][3] = fmaf(a.z, w.w, acc[2][3]);
        acc[3][0] = fmaf(a.w, w.x, acc[3][0]); acc[3][1] = fmaf(a.w, w.y, acc[3][1]);
        acc[3][2] = fmaf(a.w, w.z, acc[3][2]); acc[3][3] = fmaf(a.w, w.w, acc[3][3]);
    }
    float s0 = as2[c0], s1 = as2[c0+1], s2 = as2[c0+2], s3 = as2[c0+3];
    float d0 = ad2[c0], d1 = ad2[c0+1], d2 = ad2[c0+2], d3 = ad2[c0+3];
    #pragma unroll
    for (int i = 0; i < 4; ++i) {
        int row = blockIdx.x * 128 + r0 + i;
        float ps = acc[i][0]*s0 + acc[i][1]*s1 + acc[i][2]*s2 + acc[i][3]*s3;
        float pd = acc[i][0]*d0 + acc[i][1]*d1 + acc[i][2]*d2 + acc[i][3]*d3;
        ps += __shfl_xor(ps, 1); ps += __shfl_xor(ps, 2); ps += __shfl_xor(ps, 4);
        pd += __shfl_xor(pd, 1); pd += __shfl_xor(pd, 2); pd += __shfl_xor(pd, 4);
        if (row < NB*ND0) {
            *(float4*)&ht2[(size_t)row*32 + c0] =
                make_float4(acc[i][0], acc[i][1], acc[i][2], acc[i][3]);
            if ((t & 7) == 0) { es2[row] = ps; ed2[row] = pd; }
        }
    }
}

// ---------------- layer 2 per-dst aggregation ------------------------------
// batch-major blocks (4 dsts x 1 batch); per-batch ht2 slice 1.92 MB is
// L2-resident. Wave: 8 x 8-lane edge groups, lane = 4 channels (float4).
__global__ __launch_bounds__(256) void k7_agg2(
        const int* __restrict__ srcsort1, const int* __restrict__ off1,
        const int* __restrict__ deg1, const int* __restrict__ res1,
        const float* __restrict__ es2, const float* __restrict__ ed2,
        const float* __restrict__ ht2, const float* __restrict__ b2,
        float* __restrict__ outp) {
    int b = blockIdx.x / (ND1/4);
    int chunk = blockIdx.x - b * (ND1/4);
    int d = chunk * 4 + (threadIdx.x >> 6);
    int lane = threadIdx.x & 63;
    int grp = lane >> 3;                   // edge slot 0..7
    int c = lane & 7;                      // channel quad: channels 4c..4c+3
    int dn = res1[d];
    float edv = ed2[b*ND0 + dn];
    int start = off1[d];
    int cnt = deg1[d];
    float ax = 0.f, ay = 0.f, az = 0.f, aw = 0.f, wsum = 0.f;
    for (int i = grp; i < cnt; i += 8) {
        int s = srcsort1[start + i];
        float lg = es2[b*ND0 + s] + edv;
        float4 hv = *(const float4*)&ht2[((size_t)(b*ND0 + s))*32 + c*4];
        lg = lg > 0.f ? lg : NEG * lg;
        float w = __expf(lg);
        ax = fmaf(w, hv.x, ax);
        ay = fmaf(w, hv.y, ay);
        az = fmaf(w, hv.z, az);
        aw = fmaf(w, hv.w, aw);
        wsum += w;
    }
    ax += __shfl_xor(ax, 8); ax += __shfl_xor(ax, 16); ax += __shfl_xor(ax, 32);
    ay += __shfl_xor(ay, 8); ay += __shfl_xor(ay, 16); ay += __shfl_xor(ay, 32);
    az += __shfl_xor(az, 8); az += __shfl_xor(az, 16); az += __shfl_xor(az, 32);
    aw += __shfl_xor(aw, 8); aw += __shfl_xor(aw, 16); aw += __shfl_xor(aw, 32);
    wsum += __shfl_xor(wsum, 8); wsum += __shfl_xor(wsum, 16); wsum += __shfl_xor(wsum, 32);
    if (grp == 0) {
        float inv = cnt > 0 ? 1.f / wsum : 0.f;
        float4 bb = *(const float4*)&b2[c*4];
        float4 o;
        o.x = ax*inv + bb.x; o.y = ay*inv + bb.y;
        o.z = az*inv + bb.z; o.w = aw*inv + bb.w;
        *(float4*)&outp[((size_t)(b*ND1 + d))*32 + c*4] = o;
    }
}

extern "C" void kernel_launch(void* const* d_in, const int* in_sizes, int n_in,
                              void* d_out, int out_size, void* d_ws, size_t ws_size,
                              hipStream_t stream) {
    const float* x        = (const float*)d_in[0];
    const int*   n_id0    = (const int*)d_in[1];
    const int*   res0     = (const int*)d_in[2];
    const int*   esrc0    = (const int*)d_in[3];
    const int*   edst0    = (const int*)d_in[4];
    const int*   res1     = (const int*)d_in[5];
    const int*   esrc1    = (const int*)d_in[6];
    const int*   edst1    = (const int*)d_in[7];
    const float* W1       = (const float*)d_in[8];
    const float* a_src1   = (const float*)d_in[9];
    const float* a_dst1   = (const float*)d_in[10];
    const float* b1       = (const float*)d_in[11];
    const float* W2       = (const float*)d_in[12];
    const float* a_src2   = (const float*)d_in[13];
    const float* a_dst2   = (const float*)d_in[14];
    const float* b2       = (const float*)d_in[15];
    float* outp = (float*)d_out;

    char* base = (char*)d_ws;
    unsigned short* ht1b = (unsigned short*)base;            // 120000*64*2  = 15,360,000 B
    float* es1  = (float*)(base + 15360000);                 // 960,000 f
    float* ed1  = es1 + 960000;                              // 960,000 f
    float* agg1 = ed1 + 960000;                              // 3,840,000 f
    float* ht2  = agg1 + 3840000;                            // 1,920,000 f
    float* es2  = ht2 + 1920000;                             // 60,000 f
    float* ed2  = es2 + 60000;                               // 60,000 f
    int* deg0     = (int*)(ed2 + 60000);                     // 15000
    int* off0     = deg0 + ND0;
    int* cur0     = off0 + ND0;
    int* deg1     = cur0 + ND0;
    int* off1     = deg1 + ND1;
    int* cur1     = off1 + ND1;
    int* srcsort0 = cur1 + ND1;                              // 360000
    int* srcsort1 = srcsort0 + NE0;                          // 180000
    // total ~49.2 MB

    kz_zero<<<(ND0 + 255)/256, 256, 0, stream>>>(deg0, deg1);
    kh_hist<<<(NE0 + NE1 + 255)/256, 256, 0, stream>>>(edst0, edst1, deg0, deg1);
    ks_scan<<<2, 1024, 0, stream>>>(deg0, off0, cur0, deg1, off1, cur1);
    kc_scatter<<<(NE0 + NE1 + 255)/256, 256, 0, stream>>>(esrc0, edst0, esrc1, edst1,
                                                          cur0, cur1, srcsort0, srcsort1);
    k1_node1<<<(NB*NS0)/64, 256, 0, stream>>>(x, n_id0, W1, a_src1, a_dst1, ht1b, es1, ed1);
    k3_agg1<<<NB*(ND0/4), 256, 0, stream>>>(srcsort0, off0, deg0, res0, es1, ed1, ht1b, b1, agg1);
    k5_node2<<<(NB*ND0 + 127)/128, 256, 0, stream>>>(agg1, W2, a_src2, a_dst2, ht2, es2, ed2);
    k7_agg2<<<NB*(ND1/4), 256, 0, stream>>>(srcsort1, off1, deg1, res1, es2, ed2, ht2, b2, outp);
}

// Round 8
// 259.448 us; speedup vs baseline: 1.2841x; 1.0734x over previous
//
#include <hip/hip_runtime.h>

#define NB 4
#define NT 40000
#define NS0 30000
#define ND0 15000
#define NE0 360000
#define ND1 7500
#define NE1 180000
#define NEG 0.2f

__device__ __forceinline__ unsigned short f2bf(float f) {
    unsigned u = __float_as_uint(f);
    u += 0x7FFF + ((u >> 16) & 1);          // round-to-nearest-even
    return (unsigned short)(u >> 16);
}
// packed bf16 pair in a uint: low ushort = even channel, high = odd channel
__device__ __forceinline__ float bf_lo(unsigned u) { return __uint_as_float(u << 16); }
__device__ __forceinline__ float bf_hi(unsigned u) { return __uint_as_float(u & 0xFFFF0000u); }

// ---------------- zero degree histograms -----------------------------------
__global__ void kz_zero(int* __restrict__ deg0, int* __restrict__ deg1) {
    int t = blockIdx.x * blockDim.x + threadIdx.x;
    if (t < ND0) deg0[t] = 0;
    if (t < ND1) deg1[t] = 0;
}

// ---------------- histogram of edge destinations ---------------------------
__global__ void kh_hist(const int* __restrict__ edst0, const int* __restrict__ edst1,
                        int* __restrict__ deg0, int* __restrict__ deg1) {
    int t = blockIdx.x * blockDim.x + threadIdx.x;
    if (t < NE0) atomicAdd(&deg0[edst0[t]], 1);
    else if (t < NE0 + NE1) atomicAdd(&deg1[edst1[t - NE0]], 1);
}

// ---------------- exclusive scan (one block per layer) ---------------------
__device__ void scan_block(const int* __restrict__ deg, int* __restrict__ off,
                           int* __restrict__ cur, int n) {
    __shared__ int s[1024];
    int t = threadIdx.x;
    int chunk = (n + 1023) / 1024;
    int base = t * chunk;
    int mysum = 0;
    for (int i = 0; i < chunk; ++i) {
        int idx = base + i;
        if (idx < n) mysum += deg[idx];
    }
    s[t] = mysum;
    __syncthreads();
    for (int o = 1; o < 1024; o <<= 1) {
        int v = (t >= o) ? s[t - o] : 0;
        __syncthreads();
        s[t] += v;
        __syncthreads();
    }
    int run = s[t] - mysum;   // exclusive prefix of my chunk
    for (int i = 0; i < chunk; ++i) {
        int idx = base + i;
        if (idx < n) {
            off[idx] = run;
            cur[idx] = run;
            run += deg[idx];
        }
    }
}

__global__ void ks_scan(const int* __restrict__ deg0, int* __restrict__ off0, int* __restrict__ cur0,
                        const int* __restrict__ deg1, int* __restrict__ off1, int* __restrict__ cur1) {
    if (blockIdx.x == 0) scan_block(deg0, off0, cur0, ND0);
    else                 scan_block(deg1, off1, cur1, ND1);
}

// ---------------- scatter src ids into dst-sorted order --------------------
__global__ void kc_scatter(const int* __restrict__ esrc0, const int* __restrict__ edst0,
                           const int* __restrict__ esrc1, const int* __restrict__ edst1,
                           int* __restrict__ cur0, int* __restrict__ cur1,
                           int* __restrict__ srcsort0, int* __restrict__ srcsort1) {
    int t = blockIdx.x * blockDim.x + threadIdx.x;
    if (t < NE0) {
        int pos = atomicAdd(&cur0[edst0[t]], 1);
        srcsort0[pos] = esrc0[t];
    } else if (t < NE0 + NE1) {
        int e = t - NE0;
        int pos = atomicAdd(&cur1[edst1[e]], 1);
        srcsort1[pos] = esrc1[e];
    }
}

// ---------------- layer 1 node transform (register-blocked GEMM) -----------
__global__ __launch_bounds__(256) void k1_node1(
        const float* __restrict__ x, const int* __restrict__ n_id0,
        const float* __restrict__ W1, const float* __restrict__ a_src,
        const float* __restrict__ a_dst,
        unsigned short* __restrict__ ht1b, float* __restrict__ es1, float* __restrict__ ed1) {
    __shared__ float xt[64*68];
    __shared__ float Wl[64*64];
    __shared__ float asl[64], adl[64];
    int t = threadIdx.x;
    for (int i = t; i < 1024; i += 256)
        *(float4*)&Wl[i*4] = *(const float4*)&W1[i*4];
    if (t < 64) { asl[t] = a_src[t]; adl[t] = a_dst[t]; }
    int rr = t & 63;
    int q  = t >> 6;                       // k-quarter 0..3
    int row_s = blockIdx.x * 64 + rr;      // < 120000 always (1875*64)
    int bs = row_s / NS0;
    int ns = row_s - bs * NS0;
    const float* xrow = x + ((size_t)(bs * NT + n_id0[ns])) * 64;
    #pragma unroll
    for (int j = 0; j < 4; ++j) {
        int k = q * 16 + j * 4;
        float4 v = *(const float4*)&xrow[k];
        xt[(k+0)*68 + rr] = v.x;
        xt[(k+1)*68 + rr] = v.y;
        xt[(k+2)*68 + rr] = v.z;
        xt[(k+3)*68 + rr] = v.w;
    }
    __syncthreads();
    int c0 = (t & 15) * 4;
    int r0 = (t >> 4) * 4;
    float acc[4][4] = {};
    #pragma unroll 16
    for (int k = 0; k < 64; ++k) {
        float4 a = *(const float4*)&xt[k*68 + r0];
        float4 w = *(const float4*)&Wl[k*64 + c0];
        acc[0][0] = fmaf(a.x, w.x, acc[0][0]); acc[0][1] = fmaf(a.x, w.y, acc[0][1]);
        acc[0][2] = fmaf(a.x, w.z, acc[0][2]); acc[0][3] = fmaf(a.x, w.w, acc[0][3]);
        acc[1][0] = fmaf(a.y, w.x, acc[1][0]); acc[1][1] = fmaf(a.y, w.y, acc[1][1]);
        acc[1][2] = fmaf(a.y, w.z, acc[1][2]); acc[1][3] = fmaf(a.y, w.w, acc[1][3]);
        acc[2][0] = fmaf(a.z, w.x, acc[2][0]); acc[2][1] = fmaf(a.z, w.y, acc[2][1]);
        acc[2][2] = fmaf(a.z, w.z, acc[2][2]); acc[2][3] = fmaf(a.z, w.w, acc[2][3]);
        acc[3][0] = fmaf(a.w, w.x, acc[3][0]); acc[3][1] = fmaf(a.w, w.y, acc[3][1]);
        acc[3][2] = fmaf(a.w, w.z, acc[3][2]); acc[3][3] = fmaf(a.w, w.w, acc[3][3]);
    }
    float as0 = asl[c0], as1 = asl[c0+1], as2 = asl[c0+2], as3 = asl[c0+3];
    float ad0 = adl[c0], ad1 = adl[c0+1], ad2 = adl[c0+2], ad3 = adl[c0+3];
    int hh = (t & 15) >> 1;
    #pragma unroll
    for (int i = 0; i < 4; ++i) {
        int row = blockIdx.x * 64 + r0 + i;
        ushort4 ov;
        ov.x = f2bf(acc[i][0]); ov.y = f2bf(acc[i][1]);
        ov.z = f2bf(acc[i][2]); ov.w = f2bf(acc[i][3]);
        *(ushort4*)&ht1b[(size_t)row*64 + c0] = ov;
        float ps = acc[i][0]*as0 + acc[i][1]*as1 + acc[i][2]*as2 + acc[i][3]*as3;
        float pd = acc[i][0]*ad0 + acc[i][1]*ad1 + acc[i][2]*ad2 + acc[i][3]*ad3;
        ps += __shfl_xor(ps, 1);
        pd += __shfl_xor(pd, 1);
        if ((t & 1) == 0) {
            es1[row*8 + hh] = ps;
            ed1[row*8 + hh] = pd;
        }
    }
}

// ---------------- layer 1 per-dst aggregation ------------------------------
// batch-major blocks (4 dsts x 1 batch). Wave: 8 x 8-lane edge groups,
// lane = 1 head = 8 channels (uint4 = 16B bf16), 2-deep unroll ->
// up to 16 independent gathers in flight per wave (MLP for latency hiding).
__global__ __launch_bounds__(256) void k3_agg1(
        const int* __restrict__ srcsort0, const int* __restrict__ off0,
        const int* __restrict__ deg0, const int* __restrict__ res0,
        const float* __restrict__ es1, const float* __restrict__ ed1,
        const unsigned short* __restrict__ ht1b, const float* __restrict__ b1,
        float* __restrict__ agg1) {
    int b = blockIdx.x / (ND0/4);
    int chunk = blockIdx.x - b * (ND0/4);
    int d = chunk * 4 + (threadIdx.x >> 6);
    int lane = threadIdx.x & 63;
    int grp = lane >> 3;                   // edge slot 0..7
    int c = lane & 7;                      // head index; channels 8c..8c+7
    int dn = res0[d];
    float edv = ed1[(b*NS0 + dn)*8 + c];
    int start = off0[d];
    int cnt = deg0[d];
    float acc[8] = {};
    float wsum = 0.f;
    int i = grp;
    for (; i + 8 < cnt; i += 16) {
        int s0 = srcsort0[start + i];
        int s1 = srcsort0[start + i + 8];
        float e0 = es1[(b*NS0 + s0)*8 + c] + edv;
        float e1 = es1[(b*NS0 + s1)*8 + c] + edv;
        uint4 h0 = *(const uint4*)&ht1b[((size_t)(b*NS0 + s0))*64 + c*8];
        uint4 h1 = *(const uint4*)&ht1b[((size_t)(b*NS0 + s1))*64 + c*8];
        e0 = e0 > 0.f ? e0 : NEG * e0;
        e1 = e1 > 0.f ? e1 : NEG * e1;
        float w0 = __expf(e0), w1 = __expf(e1);
        acc[0] = fmaf(w0, bf_lo(h0.x), acc[0]); acc[1] = fmaf(w0, bf_hi(h0.x), acc[1]);
        acc[2] = fmaf(w0, bf_lo(h0.y), acc[2]); acc[3] = fmaf(w0, bf_hi(h0.y), acc[3]);
        acc[4] = fmaf(w0, bf_lo(h0.z), acc[4]); acc[5] = fmaf(w0, bf_hi(h0.z), acc[5]);
        acc[6] = fmaf(w0, bf_lo(h0.w), acc[6]); acc[7] = fmaf(w0, bf_hi(h0.w), acc[7]);
        acc[0] = fmaf(w1, bf_lo(h1.x), acc[0]); acc[1] = fmaf(w1, bf_hi(h1.x), acc[1]);
        acc[2] = fmaf(w1, bf_lo(h1.y), acc[2]); acc[3] = fmaf(w1, bf_hi(h1.y), acc[3]);
        acc[4] = fmaf(w1, bf_lo(h1.z), acc[4]); acc[5] = fmaf(w1, bf_hi(h1.z), acc[5]);
        acc[6] = fmaf(w1, bf_lo(h1.w), acc[6]); acc[7] = fmaf(w1, bf_hi(h1.w), acc[7]);
        wsum += w0 + w1;
    }
    if (i < cnt) {
        int s0 = srcsort0[start + i];
        float e0 = es1[(b*NS0 + s0)*8 + c] + edv;
        uint4 h0 = *(const uint4*)&ht1b[((size_t)(b*NS0 + s0))*64 + c*8];
        e0 = e0 > 0.f ? e0 : NEG * e0;
        float w0 = __expf(e0);
        acc[0] = fmaf(w0, bf_lo(h0.x), acc[0]); acc[1] = fmaf(w0, bf_hi(h0.x), acc[1]);
        acc[2] = fmaf(w0, bf_lo(h0.y), acc[2]); acc[3] = fmaf(w0, bf_hi(h0.y), acc[3]);
        acc[4] = fmaf(w0, bf_lo(h0.z), acc[4]); acc[5] = fmaf(w0, bf_hi(h0.z), acc[5]);
        acc[6] = fmaf(w0, bf_lo(h0.w), acc[6]); acc[7] = fmaf(w0, bf_hi(h0.w), acc[7]);
        wsum += w0;
    }
    // combine the 8 edge groups (lanes with equal c hold the same channels)
    #pragma unroll
    for (int j = 0; j < 8; ++j) {
        acc[j] += __shfl_xor(acc[j], 8);
        acc[j] += __shfl_xor(acc[j], 16);
        acc[j] += __shfl_xor(acc[j], 32);
    }
    wsum += __shfl_xor(wsum, 8); wsum += __shfl_xor(wsum, 16); wsum += __shfl_xor(wsum, 32);
    if (grp == 0) {
        float inv = cnt > 0 ? 1.f / wsum : 0.f;
        float4 b_lo = *(const float4*)&b1[c*8];
        float4 b_hi = *(const float4*)&b1[c*8 + 4];
        float o[8];
        o[0] = acc[0]*inv + b_lo.x; o[1] = acc[1]*inv + b_lo.y;
        o[2] = acc[2]*inv + b_lo.z; o[3] = acc[3]*inv + b_lo.w;
        o[4] = acc[4]*inv + b_hi.x; o[5] = acc[5]*inv + b_hi.y;
        o[6] = acc[6]*inv + b_hi.z; o[7] = acc[7]*inv + b_hi.w;
        #pragma unroll
        for (int j = 0; j < 8; ++j) o[j] = o[j] > 0.f ? o[j] : __expf(o[j]) - 1.f;
        float* orow = &agg1[((size_t)(b*ND0 + d))*64 + c*8];
        *(float4*)&orow[0] = make_float4(o[0], o[1], o[2], o[3]);
        *(float4*)&orow[4] = make_float4(o[4], o[5], o[6], o[7]);
    }
}

// ---------------- layer 2 node transform (register-blocked GEMM) -----------
__global__ __launch_bounds__(256) void k5_node2(
        const float* __restrict__ h, const float* __restrict__ W2,
        const float* __restrict__ a_src2, const float* __restrict__ a_dst2,
        float* __restrict__ ht2, float* __restrict__ es2, float* __restrict__ ed2) {
    __shared__ float xt[64*132];
    __shared__ float Wl[64*32];
    __shared__ float as2[32], ad2[32];
    int t = threadIdx.x;
    for (int i = t; i < 512; i += 256)
        *(float4*)&Wl[i*4] = *(const float4*)&W2[i*4];
    if (t < 32) { as2[t] = a_src2[t]; ad2[t] = a_dst2[t]; }
    int rr = t & 127;
    int q  = t >> 7;
    int row_s = blockIdx.x * 128 + rr;
    bool valid = row_s < NB*ND0;
    const float* hrow = h + (size_t)row_s * 64;
    #pragma unroll
    for (int j = 0; j < 8; ++j) {
        int k = q * 32 + j * 4;
        float4 v = valid ? *(const float4*)&hrow[k] : make_float4(0.f,0.f,0.f,0.f);
        xt[(k+0)*132 + rr] = v.x;
        xt[(k+1)*132 + rr] = v.y;
        xt[(k+2)*132 + rr] = v.z;
        xt[(k+3)*132 + rr] = v.w;
    }
    __syncthreads();
    int c0 = (t & 7) * 4;
    int r0 = (t >> 3) * 4;
    float acc[4][4] = {};
    #pragma unroll 16
    for (int k = 0; k < 64; ++k) {
        float4 a = *(const float4*)&xt[k*132 + r0];
        float4 w = *(const float4*)&Wl[k*32 + c0];
        acc[0][0] = fmaf(a.x, w.x, acc[0][0]); acc[0][1] = fmaf(a.x, w.y, acc[0][1]);
        acc[0][2] = fmaf(a.x, w.z, acc[0][2]); acc[0][3] = fmaf(a.x, w.w, acc[0][3]);
        acc[1][0] = fmaf(a.y, w.x, acc[1][0]); acc[1][1] = fmaf(a.y, w.y, acc[1][1]);
        acc[1][2] = fmaf(a.y, w.z, acc[1][2]); acc[1][3] = fmaf(a.y, w.w, acc[1][3]);
        acc[2][0] = fmaf(a.z, w.x, acc[2][0]); acc[2][1] = fmaf(a.z, w.y, acc[2][1]);
        acc[2][2] = fmaf(a.z, w.z, acc[2][2]); acc[2][3] = fmaf(a.z, w.w, acc[2][3]);
        acc[3][0] = fmaf(a.w, w.x, acc[3][0]); acc[3][1] = fmaf(a.w, w.y, acc[3][1]);
        acc[3][2] = fmaf(a.w, w.z, acc[3][2]); acc[3][3] = fmaf(a.w, w.w, acc[3][3]);
    }
    float s0 = as2[c0], s1 = as2[c0+1], s2 = as2[c0+2], s3 = as2[c0+3];
    float d0 = ad2[c0], d1 = ad2[c0+1], d2 = ad2[c0+2], d3 = ad2[c0+3];
    #pragma unroll
    for (int i = 0; i < 4; ++i) {
        int row = blockIdx.x * 128 + r0 + i;
        float ps = acc[i][0]*s0 + acc[i][1]*s1 + acc[i][2]*s2 + acc[i][3]*s3;
        float pd = acc[i][0]*d0 + acc[i][1]*d1 + acc[i][2]*d2 + acc[i][3]*d3;
        ps += __shfl_xor(ps, 1); ps += __shfl_xor(ps, 2); ps += __shfl_xor(ps, 4);
        pd += __shfl_xor(pd, 1); pd += __shfl_xor(pd, 2); pd += __shfl_xor(pd, 4);
        if (row < NB*ND0) {
            *(float4*)&ht2[(size_t)row*32 + c0] =
                make_float4(acc[i][0], acc[i][1], acc[i][2], acc[i][3]);
            if ((t & 7) == 0) { es2[row] = ps; ed2[row] = pd; }
        }
    }
}

// ---------------- layer 2 per-dst aggregation ------------------------------
// batch-major blocks (4 dsts x 1 batch). Wave: 8 x 8-lane edge groups,
// lane = 4 channels (float4), 2-deep unroll for MLP.
__global__ __launch_bounds__(256) void k7_agg2(
        const int* __restrict__ srcsort1, const int* __restrict__ off1,
        const int* __restrict__ deg1, const int* __restrict__ res1,
        const float* __restrict__ es2, const float* __restrict__ ed2,
        const float* __restrict__ ht2, const float* __restrict__ b2,
        float* __restrict__ outp) {
    int b = blockIdx.x / (ND1/4);
    int chunk = blockIdx.x - b * (ND1/4);
    int d = chunk * 4 + (threadIdx.x >> 6);
    int lane = threadIdx.x & 63;
    int grp = lane >> 3;                   // edge slot 0..7
    int c = lane & 7;                      // channel quad: channels 4c..4c+3
    int dn = res1[d];
    float edv = ed2[b*ND0 + dn];
    int start = off1[d];
    int cnt = deg1[d];
    float ax = 0.f, ay = 0.f, az = 0.f, aw = 0.f, wsum = 0.f;
    int i = grp;
    for (; i + 8 < cnt; i += 16) {
        int s0 = srcsort1[start + i];
        int s1 = srcsort1[start + i + 8];
        float lg0 = es2[b*ND0 + s0] + edv;
        float lg1 = es2[b*ND0 + s1] + edv;
        float4 h0 = *(const float4*)&ht2[((size_t)(b*ND0 + s0))*32 + c*4];
        float4 h1 = *(const float4*)&ht2[((size_t)(b*ND0 + s1))*32 + c*4];
        lg0 = lg0 > 0.f ? lg0 : NEG * lg0;
        lg1 = lg1 > 0.f ? lg1 : NEG * lg1;
        float w0 = __expf(lg0), w1 = __expf(lg1);
        ax = fmaf(w0, h0.x, ax); ay = fmaf(w0, h0.y, ay);
        az = fmaf(w0, h0.z, az); aw = fmaf(w0, h0.w, aw);
        ax = fmaf(w1, h1.x, ax); ay = fmaf(w1, h1.y, ay);
        az = fmaf(w1, h1.z, az); aw = fmaf(w1, h1.w, aw);
        wsum += w0 + w1;
    }
    if (i < cnt) {
        int s0 = srcsort1[start + i];
        float lg0 = es2[b*ND0 + s0] + edv;
        float4 h0 = *(const float4*)&ht2[((size_t)(b*ND0 + s0))*32 + c*4];
        lg0 = lg0 > 0.f ? lg0 : NEG * lg0;
        float w0 = __expf(lg0);
        ax = fmaf(w0, h0.x, ax); ay = fmaf(w0, h0.y, ay);
        az = fmaf(w0, h0.z, az); aw = fmaf(w0, h0.w, aw);
        wsum += w0;
    }
    ax += __shfl_xor(ax, 8); ax += __shfl_xor(ax, 16); ax += __shfl_xor(ax, 32);
    ay += __shfl_xor(ay, 8); ay += __shfl_xor(ay, 16); ay += __shfl_xor(ay, 32);
    az += __shfl_xor(az, 8); az += __shfl_xor(az, 16); az += __shfl_xor(az, 32);
    aw += __shfl_xor(aw, 8); aw += __shfl_xor(aw, 16); aw += __shfl_xor(aw, 32);
    wsum += __shfl_xor(wsum, 8); wsum += __shfl_xor(wsum, 16); wsum += __shfl_xor(wsum, 32);
    if (grp == 0) {
        float inv = cnt > 0 ? 1.f / wsum : 0.f;
        float4 bb = *(const float4*)&b2[c*4];
        float4 o;
        o.x = ax*inv + bb.x; o.y = ay*inv + bb.y;
        o.z = az*inv + bb.z; o.w = aw*inv + bb.w;
        *(float4*)&outp[((size_t)(b*ND1 + d))*32 + c*4] = o;
    }
}

extern "C" void kernel_launch(void* const* d_in, const int* in_sizes, int n_in,
                              void* d_out, int out_size, void* d_ws, size_t ws_size,
                              hipStream_t stream) {
    const float* x        = (const float*)d_in[0];
    const int*   n_id0    = (const int*)d_in[1];
    const int*   res0     = (const int*)d_in[2];
    const int*   esrc0    = (const int*)d_in[3];
    const int*   edst0    = (const int*)d_in[4];
    const int*   res1     = (const int*)d_in[5];
    const int*   esrc1    = (const int*)d_in[6];
    const int*   edst1    = (const int*)d_in[7];
    const float* W1       = (const float*)d_in[8];
    const float* a_src1   = (const float*)d_in[9];
    const float* a_dst1   = (const float*)d_in[10];
    const float* b1       = (const float*)d_in[11];
    const float* W2       = (const float*)d_in[12];
    const float* a_src2   = (const float*)d_in[13];
    const float* a_dst2   = (const float*)d_in[14];
    const float* b2       = (const float*)d_in[15];
    float* outp = (float*)d_out;

    char* base = (char*)d_ws;
    unsigned short* ht1b = (unsigned short*)base;            // 120000*64*2  = 15,360,000 B
    float* es1  = (float*)(base + 15360000);                 // 960,000 f
    float* ed1  = es1 + 960000;                              // 960,000 f
    float* agg1 = ed1 + 960000;                              // 3,840,000 f
    float* ht2  = agg1 + 3840000;                            // 1,920,000 f
    float* es2  = ht2 + 1920000;                             // 60,000 f
    float* ed2  = es2 + 60000;                               // 60,000 f
    int* deg0     = (int*)(ed2 + 60000);                     // 15000
    int* off0     = deg0 + ND0;
    int* cur0     = off0 + ND0;
    int* deg1     = cur0 + ND0;
    int* off1     = deg1 + ND1;
    int* cur1     = off1 + ND1;
    int* srcsort0 = cur1 + ND1;                              // 360000
    int* srcsort1 = srcsort0 + NE0;                          // 180000
    // total ~49.2 MB

    kz_zero<<<(ND0 + 255)/256, 256, 0, stream>>>(deg0, deg1);
    kh_hist<<<(NE0 + NE1 + 255)/256, 256, 0, stream>>>(edst0, edst1, deg0, deg1);
    ks_scan<<<2, 1024, 0, stream>>>(deg0, off0, cur0, deg1, off1, cur1);
    kc_scatter<<<(NE0 + NE1 + 255)/256, 256, 0, stream>>>(esrc0, edst0, esrc1, edst1,
                                                          cur0, cur1, srcsort0, srcsort1);
    k1_node1<<<(NB*NS0)/64, 256, 0, stream>>>(x, n_id0, W1, a_src1, a_dst1, ht1b, es1, ed1);
    k3_agg1<<<NB*(ND0/4), 256, 0, stream>>>(srcsort0, off0, deg0, res0, es1, ed1, ht1b, b1, agg1);
    k5_node2<<<(NB*ND0 + 127)/128, 256, 0, stream>>>(agg1, W2, a_src2, a_dst2, ht2, es2, ed2);
    k7_agg2<<<NB*(ND1/4), 256, 0, stream>>>(srcsort1, off1, deg1, res1, es2, ed2, ht2, b2, outp);
}

// Round 9
// 256.150 us; speedup vs baseline: 1.3006x; 1.0129x over previous
//
#include <hip/hip_runtime.h>

#define NB 4
#define NT 40000
#define NS0 30000
#define ND0 15000
#define NE0 360000
#define ND1 7500
#define NE1 180000
#define NEG 0.2f

typedef __attribute__((ext_vector_type(8))) short bf8;
typedef __attribute__((ext_vector_type(4))) float f4;

__device__ __forceinline__ unsigned short f2bf(float f) {
    unsigned u = __float_as_uint(f);
    u += 0x7FFF + ((u >> 16) & 1);          // round-to-nearest-even
    return (unsigned short)(u >> 16);
}
// packed bf16 pair in a uint: low ushort = even channel, high = odd channel
__device__ __forceinline__ float bf_lo(unsigned u) { return __uint_as_float(u << 16); }
__device__ __forceinline__ float bf_hi(unsigned u) { return __uint_as_float(u & 0xFFFF0000u); }

// ---------------- zero degree histograms -----------------------------------
__global__ void kz_zero(int* __restrict__ deg0, int* __restrict__ deg1) {
    int t = blockIdx.x * blockDim.x + threadIdx.x;
    if (t < ND0) deg0[t] = 0;
    if (t < ND1) deg1[t] = 0;
}

// ---------------- histogram of edge destinations ---------------------------
__global__ void kh_hist(const int* __restrict__ edst0, const int* __restrict__ edst1,
                        int* __restrict__ deg0, int* __restrict__ deg1) {
    int t = blockIdx.x * blockDim.x + threadIdx.x;
    if (t < NE0) atomicAdd(&deg0[edst0[t]], 1);
    else if (t < NE0 + NE1) atomicAdd(&deg1[edst1[t - NE0]], 1);
}

// ---------------- exclusive scan (one block per layer) ---------------------
__device__ void scan_block(const int* __restrict__ deg, int* __restrict__ off,
                           int* __restrict__ cur, int n) {
    __shared__ int s[1024];
    int t = threadIdx.x;
    int chunk = (n + 1023) / 1024;
    int base = t * chunk;
    int mysum = 0;
    for (int i = 0; i < chunk; ++i) {
        int idx = base + i;
        if (idx < n) mysum += deg[idx];
    }
    s[t] = mysum;
    __syncthreads();
    for (int o = 1; o < 1024; o <<= 1) {
        int v = (t >= o) ? s[t - o] : 0;
        __syncthreads();
        s[t] += v;
        __syncthreads();
    }
    int run = s[t] - mysum;   // exclusive prefix of my chunk
    for (int i = 0; i < chunk; ++i) {
        int idx = base + i;
        if (idx < n) {
            off[idx] = run;
            cur[idx] = run;
            run += deg[idx];
        }
    }
}

__global__ void ks_scan(const int* __restrict__ deg0, int* __restrict__ off0, int* __restrict__ cur0,
                        const int* __restrict__ deg1, int* __restrict__ off1, int* __restrict__ cur1) {
    if (blockIdx.x == 0) scan_block(deg0, off0, cur0, ND0);
    else                 scan_block(deg1, off1, cur1, ND1);
}

// ---------------- scatter src ids into dst-sorted order --------------------
__global__ void kc_scatter(const int* __restrict__ esrc0, const int* __restrict__ edst0,
                           const int* __restrict__ esrc1, const int* __restrict__ edst1,
                           int* __restrict__ cur0, int* __restrict__ cur1,
                           int* __restrict__ srcsort0, int* __restrict__ srcsort1) {
    int t = blockIdx.x * blockDim.x + threadIdx.x;
    if (t < NE0) {
        int pos = atomicAdd(&cur0[edst0[t]], 1);
        srcsort0[pos] = esrc0[t];
    } else if (t < NE0 + NE1) {
        int e = t - NE0;
        int pos = atomicAdd(&cur1[edst1[e]], 1);
        srcsort1[pos] = esrc1[e];
    }
}

// ---------------- layer 1 node transform (MFMA bf16 GEMM) ------------------
// 64-row tile; LDS xtb[row][k] and wtb[n][k] in bf16, pad 72 (2-way bank = free).
// Wave w: rows 16w..16w+15; 4 col-subtiles of 16; K=64 = 2 x mfma 16x16x32.
__global__ __launch_bounds__(256) void k1_node1(
        const float* __restrict__ x, const int* __restrict__ n_id0,
        const float* __restrict__ W1, const float* __restrict__ a_src,
        const float* __restrict__ a_dst,
        unsigned short* __restrict__ ht1b, float* __restrict__ es1, float* __restrict__ ed1) {
    __shared__ unsigned short xtb[64*72];
    __shared__ unsigned short wtb[64*72];
    __shared__ float asl[64], adl[64];
    int t = threadIdx.x;
    // WT staging: thread t handles W1 row k = t>>2, cols nb..nb+15 -> wtb[n][k]
    {
        int k = t >> 2, nb = (t & 3) * 16;
        const float* wrow = &W1[k*64 + nb];
        #pragma unroll
        for (int j = 0; j < 16; j += 4) {
            float4 v = *(const float4*)&wrow[j];
            wtb[(nb+j+0)*72 + k] = f2bf(v.x);
            wtb[(nb+j+1)*72 + k] = f2bf(v.y);
            wtb[(nb+j+2)*72 + k] = f2bf(v.z);
            wtb[(nb+j+3)*72 + k] = f2bf(v.w);
        }
    }
    if (t < 64) { asl[t] = a_src[t]; adl[t] = a_dst[t]; }
    // X staging (gathered rows -> bf16)
    {
        int rr = t & 63;
        int q4 = t >> 6;
        int row_s = blockIdx.x * 64 + rr;           // < 120000 (1875*64)
        int bs = row_s / NS0;
        int ns = row_s - bs * NS0;
        const float* xrow = x + ((size_t)(bs * NT + n_id0[ns])) * 64;
        #pragma unroll
        for (int j = 0; j < 4; ++j) {
            int k = q4 * 16 + j * 4;
            float4 v = *(const float4*)&xrow[k];
            ushort4 u;
            u.x = f2bf(v.x); u.y = f2bf(v.y); u.z = f2bf(v.z); u.w = f2bf(v.w);
            *(ushort4*)&xtb[rr*72 + k] = u;
        }
    }
    __syncthreads();
    int w = t >> 6, lane = t & 63, quad = lane >> 4, cl = lane & 15;
    int arow = 16*w + cl;
    bf8 a0 = *(const bf8*)&xtb[arow*72 + quad*8];        // A[m=cl][k=quad*8+j]
    bf8 a1 = *(const bf8*)&xtb[arow*72 + 32 + quad*8];   // k+32
    f4 acc[4];
    #pragma unroll
    for (int sub = 0; sub < 4; ++sub) {
        int n = sub*16 + cl;
        bf8 b0 = *(const bf8*)&wtb[n*72 + quad*8];       // B[k][n=cl]
        bf8 b1 = *(const bf8*)&wtb[n*72 + 32 + quad*8];
        f4 c = {0.f, 0.f, 0.f, 0.f};
        c = __builtin_amdgcn_mfma_f32_16x16x32_bf16(a0, b0, c, 0, 0, 0);
        c = __builtin_amdgcn_mfma_f32_16x16x32_bf16(a1, b1, c, 0, 0, 0);
        acc[sub] = c;
    }
    // C/D: col = sub*16+cl, row(global) = base + 16w + quad*4 + r
    int rbase = blockIdx.x*64 + 16*w + quad*4;
    #pragma unroll
    for (int sub = 0; sub < 4; ++sub)
        #pragma unroll
        for (int r = 0; r < 4; ++r)
            ht1b[(size_t)(rbase + r)*64 + sub*16 + cl] = f2bf(acc[sub][r]);
    // es/ed: per row, per head (8 cols); reduce over cl low-3 bits
    #pragma unroll
    for (int r = 0; r < 4; ++r) {
        #pragma unroll
        for (int sub = 0; sub < 4; ++sub) {
            int col = sub*16 + cl;
            float ps = acc[sub][r] * asl[col];
            float pd = acc[sub][r] * adl[col];
            ps += __shfl_xor(ps, 1); ps += __shfl_xor(ps, 2); ps += __shfl_xor(ps, 4);
            pd += __shfl_xor(pd, 1); pd += __shfl_xor(pd, 2); pd += __shfl_xor(pd, 4);
            if ((cl & 7) == 0) {
                int h = sub*2 + (cl >> 3);
                es1[(rbase + r)*8 + h] = ps;
                ed1[(rbase + r)*8 + h] = pd;
            }
        }
    }
}

// ---------------- layer 1 per-dst aggregation ------------------------------
// batch-major blocks (4 dsts x 1 batch). Wave: 8 x 8-lane edge groups,
// lane = 1 head = 8 channels (uint4 16B bf16), 2-deep unroll + index
// prefetch (breaks srcsort->gather dependent chain).
__global__ __launch_bounds__(256) void k3_agg1(
        const int* __restrict__ srcsort0, const int* __restrict__ off0,
        const int* __restrict__ deg0, const int* __restrict__ res0,
        const float* __restrict__ es1, const float* __restrict__ ed1,
        const unsigned short* __restrict__ ht1b, const float* __restrict__ b1,
        float* __restrict__ agg1) {
    int b = blockIdx.x / (ND0/4);
    int chunk = blockIdx.x - b * (ND0/4);
    int d = chunk * 4 + (threadIdx.x >> 6);
    int lane = threadIdx.x & 63;
    int grp = lane >> 3;                   // edge slot 0..7
    int c = lane & 7;                      // head index; channels 8c..8c+7
    int dn = res0[d];
    float edv = ed1[(b*NS0 + dn)*8 + c];
    int start = off0[d];
    int cnt = deg0[d];
    float acc[8] = {};
    float wsum = 0.f;
    int i = grp;
    int sA = (i < cnt) ? srcsort0[start + i] : 0;
    int sB = (i + 8 < cnt) ? srcsort0[start + i + 8] : 0;
    while (i + 8 < cnt) {
        int inx = i + 16;
        int pA = (inx < cnt) ? srcsort0[start + inx] : 0;
        int pB = (inx + 8 < cnt) ? srcsort0[start + inx + 8] : 0;
        float e0 = es1[(b*NS0 + sA)*8 + c] + edv;
        float e1 = es1[(b*NS0 + sB)*8 + c] + edv;
        uint4 h0 = *(const uint4*)&ht1b[((size_t)(b*NS0 + sA))*64 + c*8];
        uint4 h1 = *(const uint4*)&ht1b[((size_t)(b*NS0 + sB))*64 + c*8];
        e0 = e0 > 0.f ? e0 : NEG * e0;
        e1 = e1 > 0.f ? e1 : NEG * e1;
        float w0 = __expf(e0), w1 = __expf(e1);
        acc[0] = fmaf(w0, bf_lo(h0.x), acc[0]); acc[1] = fmaf(w0, bf_hi(h0.x), acc[1]);
        acc[2] = fmaf(w0, bf_lo(h0.y), acc[2]); acc[3] = fmaf(w0, bf_hi(h0.y), acc[3]);
        acc[4] = fmaf(w0, bf_lo(h0.z), acc[4]); acc[5] = fmaf(w0, bf_hi(h0.z), acc[5]);
        acc[6] = fmaf(w0, bf_lo(h0.w), acc[6]); acc[7] = fmaf(w0, bf_hi(h0.w), acc[7]);
        acc[0] = fmaf(w1, bf_lo(h1.x), acc[0]); acc[1] = fmaf(w1, bf_hi(h1.x), acc[1]);
        acc[2] = fmaf(w1, bf_lo(h1.y), acc[2]); acc[3] = fmaf(w1, bf_hi(h1.y), acc[3]);
        acc[4] = fmaf(w1, bf_lo(h1.z), acc[4]); acc[5] = fmaf(w1, bf_hi(h1.z), acc[5]);
        acc[6] = fmaf(w1, bf_lo(h1.w), acc[6]); acc[7] = fmaf(w1, bf_hi(h1.w), acc[7]);
        wsum += w0 + w1;
        sA = pA; sB = pB; i = inx;
    }
    if (i < cnt) {   // at most one edge left in this slot; sA is valid
        float e0 = es1[(b*NS0 + sA)*8 + c] + edv;
        uint4 h0 = *(const uint4*)&ht1b[((size_t)(b*NS0 + sA))*64 + c*8];
        e0 = e0 > 0.f ? e0 : NEG * e0;
        float w0 = __expf(e0);
        acc[0] = fmaf(w0, bf_lo(h0.x), acc[0]); acc[1] = fmaf(w0, bf_hi(h0.x), acc[1]);
        acc[2] = fmaf(w0, bf_lo(h0.y), acc[2]); acc[3] = fmaf(w0, bf_hi(h0.y), acc[3]);
        acc[4] = fmaf(w0, bf_lo(h0.z), acc[4]); acc[5] = fmaf(w0, bf_hi(h0.z), acc[5]);
        acc[6] = fmaf(w0, bf_lo(h0.w), acc[6]); acc[7] = fmaf(w0, bf_hi(h0.w), acc[7]);
        wsum += w0;
    }
    #pragma unroll
    for (int j = 0; j < 8; ++j) {
        acc[j] += __shfl_xor(acc[j], 8);
        acc[j] += __shfl_xor(acc[j], 16);
        acc[j] += __shfl_xor(acc[j], 32);
    }
    wsum += __shfl_xor(wsum, 8); wsum += __shfl_xor(wsum, 16); wsum += __shfl_xor(wsum, 32);
    if (grp == 0) {
        float inv = cnt > 0 ? 1.f / wsum : 0.f;
        float4 b_lo = *(const float4*)&b1[c*8];
        float4 b_hi = *(const float4*)&b1[c*8 + 4];
        float o[8];
        o[0] = acc[0]*inv + b_lo.x; o[1] = acc[1]*inv + b_lo.y;
        o[2] = acc[2]*inv + b_lo.z; o[3] = acc[3]*inv + b_lo.w;
        o[4] = acc[4]*inv + b_hi.x; o[5] = acc[5]*inv + b_hi.y;
        o[6] = acc[6]*inv + b_hi.z; o[7] = acc[7]*inv + b_hi.w;
        #pragma unroll
        for (int j = 0; j < 8; ++j) o[j] = o[j] > 0.f ? o[j] : __expf(o[j]) - 1.f;
        float* orow = &agg1[((size_t)(b*ND0 + d))*64 + c*8];
        *(float4*)&orow[0] = make_float4(o[0], o[1], o[2], o[3]);
        *(float4*)&orow[4] = make_float4(o[4], o[5], o[6], o[7]);
    }
}

// ---------------- layer 2 node transform (register-blocked GEMM) -----------
__global__ __launch_bounds__(256) void k5_node2(
        const float* __restrict__ h, const float* __restrict__ W2,
        const float* __restrict__ a_src2, const float* __restrict__ a_dst2,
        float* __restrict__ ht2, float* __restrict__ es2, float* __restrict__ ed2) {
    __shared__ float xt[64*132];
    __shared__ float Wl[64*32];
    __shared__ float as2[32], ad2[32];
    int t = threadIdx.x;
    for (int i = t; i < 512; i += 256)
        *(float4*)&Wl[i*4] = *(const float4*)&W2[i*4];
    if (t < 32) { as2[t] = a_src2[t]; ad2[t] = a_dst2[t]; }
    int rr = t & 127;
    int q  = t >> 7;
    int row_s = blockIdx.x * 128 + rr;
    bool valid = row_s < NB*ND0;
    const float* hrow = h + (size_t)row_s * 64;
    #pragma unroll
    for (int j = 0; j < 8; ++j) {
        int k = q * 32 + j * 4;
        float4 v = valid ? *(const float4*)&hrow[k] : make_float4(0.f,0.f,0.f,0.f);
        xt[(k+0)*132 + rr] = v.x;
        xt[(k+1)*132 + rr] = v.y;
        xt[(k+2)*132 + rr] = v.z;
        xt[(k+3)*132 + rr] = v.w;
    }
    __syncthreads();
    int c0 = (t & 7) * 4;
    int r0 = (t >> 3) * 4;
    float acc[4][4] = {};
    #pragma unroll 16
    for (int k = 0; k < 64; ++k) {
        float4 a = *(const float4*)&xt[k*132 + r0];
        float4 w = *(const float4*)&Wl[k*32 + c0];
        acc[0][0] = fmaf(a.x, w.x, acc[0][0]); acc[0][1] = fmaf(a.x, w.y, acc[0][1]);
        acc[0][2] = fmaf(a.x, w.z, acc[0][2]); acc[0][3] = fmaf(a.x, w.w, acc[0][3]);
        acc[1][0] = fmaf(a.y, w.x, acc[1][0]); acc[1][1] = fmaf(a.y, w.y, acc[1][1]);
        acc[1][2] = fmaf(a.y, w.z, acc[1][2]); acc[1][3] = fmaf(a.y, w.w, acc[1][3]);
        acc[2][0] = fmaf(a.z, w.x, acc[2][0]); acc[2][1] = fmaf(a.z, w.y, acc[2][1]);
        acc[2][2] = fmaf(a.z, w.z, acc[2][2]); acc[2][3] = fmaf(a.z, w.w, acc[2][3]);
        acc[3][0] = fmaf(a.w, w.x, acc[3][0]); acc[3][1] = fmaf(a.w, w.y, acc[3][1]);
        acc[3][2] = fmaf(a.w, w.z, acc[3][2]); acc[3][3] = fmaf(a.w, w.w, acc[3][3]);
    }
    float s0 = as2[c0], s1 = as2[c0+1], s2 = as2[c0+2], s3 = as2[c0+3];
    float d0 = ad2[c0], d1 = ad2[c0+1], d2 = ad2[c0+2], d3 = ad2[c0+3];
    #pragma unroll
    for (int i = 0; i < 4; ++i) {
        int row = blockIdx.x * 128 + r0 + i;
        float ps = acc[i][0]*s0 + acc[i][1]*s1 + acc[i][2]*s2 + acc[i][3]*s3;
        float pd = acc[i][0]*d0 + acc[i][1]*d1 + acc[i][2]*d2 + acc[i][3]*d3;
        ps += __shfl_xor(ps, 1); ps += __shfl_xor(ps, 2); ps += __shfl_xor(ps, 4);
        pd += __shfl_xor(pd, 1); pd += __shfl_xor(pd, 2); pd += __shfl_xor(pd, 4);
        if (row < NB*ND0) {
            *(float4*)&ht2[(size_t)row*32 + c0] =
                make_float4(acc[i][0], acc[i][1], acc[i][2], acc[i][3]);
            if ((t & 7) == 0) { es2[row] = ps; ed2[row] = pd; }
        }
    }
}

// ---------------- layer 2 per-dst aggregation ------------------------------
// batch-major blocks; wave: 8 x 8-lane edge groups, lane = 4 channels
// (float4), 2-deep unroll + index prefetch.
__global__ __launch_bounds__(256) void k7_agg2(
        const int* __restrict__ srcsort1, const int* __restrict__ off1,
        const int* __restrict__ deg1, const int* __restrict__ res1,
        const float* __restrict__ es2, const float* __restrict__ ed2,
        const float* __restrict__ ht2, const float* __restrict__ b2,
        float* __restrict__ outp) {
    int b = blockIdx.x / (ND1/4);
    int chunk = blockIdx.x - b * (ND1/4);
    int d = chunk * 4 + (threadIdx.x >> 6);
    int lane = threadIdx.x & 63;
    int grp = lane >> 3;                   // edge slot 0..7
    int c = lane & 7;                      // channel quad: channels 4c..4c+3
    int dn = res1[d];
    float edv = ed2[b*ND0 + dn];
    int start = off1[d];
    int cnt = deg1[d];
    float ax = 0.f, ay = 0.f, az = 0.f, aw = 0.f, wsum = 0.f;
    int i = grp;
    int sA = (i < cnt) ? srcsort1[start + i] : 0;
    int sB = (i + 8 < cnt) ? srcsort1[start + i + 8] : 0;
    while (i + 8 < cnt) {
        int inx = i + 16;
        int pA = (inx < cnt) ? srcsort1[start + inx] : 0;
        int pB = (inx + 8 < cnt) ? srcsort1[start + inx + 8] : 0;
        float lg0 = es2[b*ND0 + sA] + edv;
        float lg1 = es2[b*ND0 + sB] + edv;
        float4 h0 = *(const float4*)&ht2[((size_t)(b*ND0 + sA))*32 + c*4];
        float4 h1 = *(const float4*)&ht2[((size_t)(b*ND0 + sB))*32 + c*4];
        lg0 = lg0 > 0.f ? lg0 : NEG * lg0;
        lg1 = lg1 > 0.f ? lg1 : NEG * lg1;
        float w0 = __expf(lg0), w1 = __expf(lg1);
        ax = fmaf(w0, h0.x, ax); ay = fmaf(w0, h0.y, ay);
        az = fmaf(w0, h0.z, az); aw = fmaf(w0, h0.w, aw);
        ax = fmaf(w1, h1.x, ax); ay = fmaf(w1, h1.y, ay);
        az = fmaf(w1, h1.z, az); aw = fmaf(w1, h1.w, aw);
        wsum += w0 + w1;
        sA = pA; sB = pB; i = inx;
    }
    if (i < cnt) {
        float lg0 = es2[b*ND0 + sA] + edv;
        float4 h0 = *(const float4*)&ht2[((size_t)(b*ND0 + sA))*32 + c*4];
        lg0 = lg0 > 0.f ? lg0 : NEG * lg0;
        float w0 = __expf(lg0);
        ax = fmaf(w0, h0.x, ax); ay = fmaf(w0, h0.y, ay);
        az = fmaf(w0, h0.z, az); aw = fmaf(w0, h0.w, aw);
        wsum += w0;
    }
    ax += __shfl_xor(ax, 8); ax += __shfl_xor(ax, 16); ax += __shfl_xor(ax, 32);
    ay += __shfl_xor(ay, 8); ay += __shfl_xor(ay, 16); ay += __shfl_xor(ay, 32);
    az += __shfl_xor(az, 8); az += __shfl_xor(az, 16); az += __shfl_xor(az, 32);
    aw += __shfl_xor(aw, 8); aw += __shfl_xor(aw, 16); aw += __shfl_xor(aw, 32);
    wsum += __shfl_xor(wsum, 8); wsum += __shfl_xor(wsum, 16); wsum += __shfl_xor(wsum, 32);
    if (grp == 0) {
        float inv = cnt > 0 ? 1.f / wsum : 0.f;
        float4 bb = *(const float4*)&b2[c*4];
        float4 o;
        o.x = ax*inv + bb.x; o.y = ay*inv + bb.y;
        o.z = az*inv + bb.z; o.w = aw*inv + bb.w;
        *(float4*)&outp[((size_t)(b*ND1 + d))*32 + c*4] = o;
    }
}

extern "C" void kernel_launch(void* const* d_in, const int* in_sizes, int n_in,
                              void* d_out, int out_size, void* d_ws, size_t ws_size,
                              hipStream_t stream) {
    const float* x        = (const float*)d_in[0];
    const int*   n_id0    = (const int*)d_in[1];
    const int*   res0     = (const int*)d_in[2];
    const int*   esrc0    = (const int*)d_in[3];
    const int*   edst0    = (const int*)d_in[4];
    const int*   res1     = (const int*)d_in[5];
    const int*   esrc1    = (const int*)d_in[6];
    const int*   edst1    = (const int*)d_in[7];
    const float* W1       = (const float*)d_in[8];
    const float* a_src1   = (const float*)d_in[9];
    const float* a_dst1   = (const float*)d_in[10];
    const float* b1       = (const float*)d_in[11];
    const float* W2       = (const float*)d_in[12];
    const float* a_src2   = (const float*)d_in[13];
    const float* a_dst2   = (const float*)d_in[14];
    const float* b2       = (const float*)d_in[15];
    float* outp = (float*)d_out;

    char* base = (char*)d_ws;
    unsigned short* ht1b = (unsigned short*)base;            // 120000*64*2  = 15,360,000 B
    float* es1  = (float*)(base + 15360000);                 // 960,000 f
    float* ed1  = es1 + 960000;                              // 960,000 f
    float* agg1 = ed1 + 960000;                              // 3,840,000 f
    float* ht2  = agg1 + 3840000;                            // 1,920,000 f
    float* es2  = ht2 + 1920000;                             // 60,000 f
    float* ed2  = es2 + 60000;                               // 60,000 f
    int* deg0     = (int*)(ed2 + 60000);                     // 15000
    int* off0     = deg0 + ND0;
    int* cur0     = off0 + ND0;
    int* deg1     = cur0 + ND0;
    int* off1     = deg1 + ND1;
    int* cur1     = off1 + ND1;
    int* srcsort0 = cur1 + ND1;                              // 360000
    int* srcsort1 = srcsort0 + NE0;                          // 180000
    // total ~49.2 MB

    kz_zero<<<(ND0 + 255)/256, 256, 0, stream>>>(deg0, deg1);
    kh_hist<<<(NE0 + NE1 + 255)/256, 256, 0, stream>>>(edst0, edst1, deg0, deg1);
    ks_scan<<<2, 1024, 0, stream>>>(deg0, off0, cur0, deg1, off1, cur1);
    kc_scatter<<<(NE0 + NE1 + 255)/256, 256, 0, stream>>>(esrc0, edst0, esrc1, edst1,
                                                          cur0, cur1, srcsort0, srcsort1);
    k1_node1<<<(NB*NS0)/64, 256, 0, stream>>>(x, n_id0, W1, a_src1, a_dst1, ht1b, es1, ed1);
    k3_agg1<<<NB*(ND0/4), 256, 0, stream>>>(srcsort0, off0, deg0, res0, es1, ed1, ht1b, b1, agg1);
    k5_node2<<<(NB*ND0 + 127)/128, 256, 0, stream>>>(agg1, W2, a_src2, a_dst2, ht2, es2, ed2);
    k7_agg2<<<NB*(ND1/4), 256, 0, stream>>>(srcsort1, off1, deg1, res1, es2, ed2, ht2, b2, outp);
}